// Round 8
// baseline (381.590 us; speedup 1.0000x reference)
//
#include <hip/hip_runtime.h>

#define NN 50000
#define NE 1600000
#define INDIM 256
#define HIDIM 128
#define OUTDIM 64

#define NRANGE 128
#define RSPAN 400             // 125 full ranges (50000 = 125*400), ranges 125..127 empty
#define ACAP 16384            // per-range staging capacity (uint records), +31 sigma
#define NBBLK 1563            // bucket blocks: (NE + 1023) / 1024
#define NDEG 256              // degree histogram bins (Poisson(32): max deg ~70)
#define NG1 196               // gemm1 super-blocks in fused kernel (196*4 = 784 >= 782)

typedef unsigned int uint;
typedef unsigned long long ull;
typedef unsigned short ushort;
typedef __attribute__((ext_vector_type(8))) short bf16x8;
typedef __attribute__((ext_vector_type(4))) float f32x4;

__device__ __forceinline__ ushort f2bf(float f) {
    uint u = __float_as_uint(f);
    uint r = (u + 0x7FFFu + ((u >> 16) & 1u)) >> 16;   // RTNE
    return (ushort)r;
}
__device__ __forceinline__ uint pk2(float a, float b) {
    return (uint)f2bf(a) | ((uint)f2bf(b) << 16);
}
__device__ __forceinline__ float bf_lo(uint u) { return __uint_as_float(u << 16); }
__device__ __forceinline__ float bf_hi(uint u) { return __uint_as_float(u & 0xFFFF0000u); }

// accumulate 8 bf16 features from a uint4
#define ACC8(u) do { \
    a0 += bf_lo((u).x); a1 += bf_hi((u).x); \
    a2 += bf_lo((u).y); a3 += bf_hi((u).y); \
    a4 += bf_lo((u).z); a5 += bf_hi((u).z); \
    a6 += bf_lo((u).w); a7 += bf_hi((u).w); \
} while (0)

// ---------------- weight transpose + bf16 convert; zero deg --------------------------

__global__ void k_wt(const float* __restrict__ W1, const float* __restrict__ W2,
                     ushort* __restrict__ W1T, ushort* __restrict__ W2T,
                     int* __restrict__ deg) {
    int idx = blockIdx.x * 256 + threadIdx.x;
    for (int i = idx; i < NN; i += gridDim.x * 256) deg[i] = 0;
    if (idx < INDIM * HIDIM) {
        int k = idx / HIDIM, nn = idx % HIDIM;
        W1T[nn * INDIM + k] = f2bf(W1[idx]);
    } else {
        int j = idx - INDIM * HIDIM;
        if (j < HIDIM * OUTDIM) {
            int k = j / OUTDIM, nn = j % OUTDIM;
            W2T[nn * HIDIM + k] = f2bf(W2[j]);
        }
    }
}

// ---------------- A1: per-block range counts + global degree count -------------------

__global__ void k_bcnt(const int* __restrict__ col, int* __restrict__ bcnt,
                       int* __restrict__ deg) {
    __shared__ int bins[NRANGE];
    int tid = threadIdx.x;
    if (tid < NRANGE) bins[tid] = 0;
    __syncthreads();
    int base = blockIdx.x * 1024 + tid;
#pragma unroll
    for (int k = 0; k < 4; k++) {
        int i = base + k * 256;
        if (i < NE) {
            int d = col[i];
            atomicAdd(&bins[d / RSPAN], 1);
            atomicAdd(&deg[d], 1);
        }
    }
    __syncthreads();
    if (tid < NRANGE) bcnt[tid * NBBLK + blockIdx.x] = bins[tid];
}

// ---------------- A2: per-range exclusive scan of block counts; dinv from deg --------

__global__ void k_bscan(const int* __restrict__ bcnt, int* __restrict__ bbase,
                        int* __restrict__ rcur, const int* __restrict__ deg,
                        float* __restrict__ dinv) {
    __shared__ int wsum[16];
    __shared__ int woff[16];
    int r = blockIdx.x;
    const int* src = bcnt + r * NBBLK;
    int* dst = bbase + r * NBBLK;
    int tid = threadIdx.x, lane = tid & 63, wid = tid >> 6;
    int gid = r * 1024 + tid;
    if (gid < NN) dinv[gid] = rsqrtf((float)(deg[gid] + 1));   // +1 self loop
    int seg = tid * 2;
    int l0 = (seg < NBBLK) ? src[seg] : 0;
    int l1 = (seg + 1 < NBBLK) ? src[seg + 1] : 0;
    int sum = l0 + l1;
    int incl = sum;
#pragma unroll
    for (int off = 1; off < 64; off <<= 1) {
        int t = __shfl_up(incl, off);
        if (lane >= off) incl += t;
    }
    if (lane == 63) wsum[wid] = incl;
    __syncthreads();
    if (wid == 0 && lane < 16) {
        int wv = wsum[lane];
        int wincl = wv;
#pragma unroll
        for (int off = 1; off < 16; off <<= 1) {
            int t = __shfl_up(wincl, off);
            if (lane >= off) wincl += t;
        }
        woff[lane] = wincl - wv;
    }
    __syncthreads();
    int run = incl - sum + woff[wid];
    if (seg < NBBLK) dst[seg] = run;
    if (seg + 1 < NBBLK) dst[seg + 1] = run + l0;
    if (tid == 1023) rcur[r] = run + sum;
}

// ---------------- A3: block-granular scatter to staged (LDS cursors) -----------------

__global__ void k_bscat(const int* __restrict__ row, const int* __restrict__ col,
                        const int* __restrict__ bbase, uint* __restrict__ staged) {
    __shared__ int cur[NRANGE];
    int tid = threadIdx.x;
    if (tid < NRANGE) cur[tid] = bbase[tid * NBBLK + blockIdx.x];
    __syncthreads();
    int base = blockIdx.x * 1024 + tid;
#pragma unroll
    for (int k = 0; k < 4; k++) {
        int i = base + k * 256;
        if (i < NE) {
            int d = col[i], s = row[i];
            int r = d / RSPAN;
            int off = atomicAdd(&cur[r], 1);
            staged[(size_t)r * ACAP + off] = ((uint)s << 10) | (uint)(d - r * RSPAN);
        }
    }
}

// ---------------- k_sg1: FUSED {counting+degree sort} || {GEMM1} ---------------------
// blocks [0,NRANGE): per-range counting sort + range-local degree sort -> perm-ordered
//   CSR (row_ptr_p, ssrc_p, dinv_p, perm). Sort fills ~half the CUs; gemm1 blocks
//   co-schedule on the rest, hiding sort's serialization.
// blocks [NRANGE, NRANGE+NG1): GEMM1 x[n][256] @ W1 -> g1s [4][NN][32] bf16, 4 sub-
//   tiles of 64 rows per 1024-thread block, shared Bs stage.

__global__ __launch_bounds__(1024) void k_sg1(
        const uint* __restrict__ staged, const int* __restrict__ rcur,
        float* __restrict__ dinv_p, int* __restrict__ row_ptr_p,
        int* __restrict__ perm, ushort* __restrict__ ssrc_p,
        const float* __restrict__ A, const ushort* __restrict__ W1T,
        const float* __restrict__ dinv, ushort* __restrict__ g1s, int n) {
    __shared__ int bins[RSPAN];
    __shared__ int pdeg[RSPAN];
    __shared__ int prow[RSPAN];
    __shared__ int lperm[RSPAN];
    __shared__ int dh[NDEG];
    __shared__ int wsum[16];
    __shared__ int woff[16];
    __shared__ ushort As[4 * 64 * 40];
    __shared__ ushort Bs[128 * 40];

    int tid = threadIdx.x, lane = tid & 63, wid = tid >> 6;

    if (blockIdx.x < NRANGE) {
        // ---------------- sort path ----------------
        int r = blockIdx.x;
        int lo = r * RSPAN;
        int count = rcur[r];
        int rbase = 0;
        for (int rr = 0; rr < r; rr++) rbase += rcur[rr];
        if (lo >= NN) {                              // empty tail ranges (125..127)
            if (lo == NN && tid == 0) row_ptr_p[NN] = rbase;   // rbase == NE here
            return;
        }
        const uint* st = staged + (size_t)r * ACAP;

        if (tid < RSPAN) bins[tid] = 0;
        if (tid < NDEG) dh[tid] = 0;
        __syncthreads();

        // pass 1: count per-node degree
        for (int i = tid; i < count; i += 1024)
            atomicAdd(&bins[st[i] & 1023u], 1);
        __syncthreads();

        int deg = (tid < RSPAN) ? bins[tid] : 0;
        bool valid = tid < RSPAN;                    // non-empty ranges are exactly full
        if (valid) atomicAdd(&dh[min(deg, NDEG - 1)], 1);
        __syncthreads();

        // exclusive scan of dh[256] by wave 0 (4 bins/lane) -> class bases (in place)
        if (wid == 0) {
            int b = lane * 4;
            int v0 = dh[b], v1 = dh[b + 1], v2 = dh[b + 2], v3 = dh[b + 3];
            int s = v0 + v1 + v2 + v3;
            int incl = s;
#pragma unroll
            for (int off = 1; off < 64; off <<= 1) {
                int t = __shfl_up(incl, off);
                if (lane >= off) incl += t;
            }
            int excl = incl - s;
            dh[b] = excl;
            dh[b + 1] = excl + v0;
            dh[b + 2] = excl + v0 + v1;
            dh[b + 3] = excl + v0 + v1 + v2;
        }
        __syncthreads();

        // local perm rank (atomic ticket within degree class)
        int rl = 0;
        if (valid) rl = atomicAdd(&dh[min(deg, NDEG - 1)], 1);
        if (valid) { pdeg[rl] = deg; lperm[rl] = tid; }
        __syncthreads();

        // exclusive scan of pdeg[RSPAN] -> prow
        int v = (tid < RSPAN) ? pdeg[tid] : 0;
        int incl = v;
#pragma unroll
        for (int off = 1; off < 64; off <<= 1) {
            int t = __shfl_up(incl, off);
            if (lane >= off) incl += t;
        }
        if (lane == 63) wsum[wid] = incl;
        __syncthreads();
        if (wid == 0 && lane < 16) {
            int wv = wsum[lane];
            int wincl = wv;
#pragma unroll
            for (int off = 1; off < 16; off <<= 1) {
                int t = __shfl_up(wincl, off);
                if (lane >= off) wincl += t;
            }
            woff[lane] = wincl - wv;
        }
        __syncthreads();
        int excl = incl - v + woff[wid];
        if (tid < RSPAN) prow[tid] = excl;
        __syncthreads();

        // permuted CSR metadata (streaming writes)
        if (tid < RSPAN) {
            int di = lo + tid;
            row_ptr_p[di] = rbase + prow[tid];
            perm[di] = lo + lperm[tid];
            dinv_p[di] = rsqrtf((float)(pdeg[tid] + 1));
        }
        __syncthreads();
        if (valid) bins[tid] = rbase + prow[rl];     // pass-2 cursors by dloc
        __syncthreads();

        // pass 2: scatter to exact perm-ordered CSR slots
        for (int i = tid; i < count; i += 1024) {
            uint rec = st[i];
            int pos = atomicAdd(&bins[rec & 1023u], 1);
            ssrc_p[pos] = (ushort)(rec >> 10);
        }
    } else {
        // ---------------- gemm1 path: 4 x 64-row tiles, shared Bs ----------------
        int sub = blockIdx.x - NRANGE;
        int g = tid >> 8;                 // sub-group 0..3
        int t256 = tid & 255;
        int w = t256 >> 6;
        int l256 = t256 & 63;
        int ln = l256 & 15, quad = l256 >> 4;
        int row0 = (sub * 4 + g) * 64;
        int n0 = w * 32;
        ushort* Asg = As + g * (64 * 40);

        f32x4 acc[4][2];
#pragma unroll
        for (int m = 0; m < 4; m++)
#pragma unroll
            for (int t = 0; t < 2; t++) acc[m][t] = (f32x4){0.f, 0.f, 0.f, 0.f};

        int ar = t256 >> 2;
        int ac = (t256 & 3) * 8;

        for (int k0 = 0; k0 < INDIM; k0 += 32) {
            {   // stage A: 64 rows x 32 k per sub-group, f32 -> bf16
                int gr = row0 + ar;
                uint4 u = make_uint4(0, 0, 0, 0);
                if (gr < n) {
                    const float* p = A + (size_t)gr * INDIM + k0 + ac;
                    float4 v0 = *(const float4*)p;
                    float4 v1 = *(const float4*)(p + 4);
                    u.x = pk2(v0.x, v0.y); u.y = pk2(v0.z, v0.w);
                    u.z = pk2(v1.x, v1.y); u.w = pk2(v1.z, v1.w);
                }
                *(uint4*)(Asg + ar * 40 + ac) = u;
            }
            if (tid < 512) {   // stage B once for all 4 sub-tiles: 128 rows x 32 k
                int bn = tid >> 2, bc = (tid & 3) * 8;
                uint4 u = *(const uint4*)(W1T + (size_t)bn * INDIM + k0 + bc);
                *(uint4*)(Bs + bn * 40 + bc) = u;
            }
            __syncthreads();

            bf16x8 af[4], bf[2];
#pragma unroll
            for (int m = 0; m < 4; m++)
                af[m] = *(const bf16x8*)(Asg + (m * 16 + ln) * 40 + quad * 8);
#pragma unroll
            for (int t = 0; t < 2; t++)
                bf[t] = *(const bf16x8*)(Bs + (n0 + t * 16 + ln) * 40 + quad * 8);
#pragma unroll
            for (int m = 0; m < 4; m++)
#pragma unroll
                for (int t = 0; t < 2; t++)
                    acc[m][t] = __builtin_amdgcn_mfma_f32_16x16x32_bf16(af[m], bf[t], acc[m][t], 0, 0, 0);
            __syncthreads();
        }

        // epilogue: w-group's 32 features == slice w of g1s [4][NN][32]
#pragma unroll
        for (int m = 0; m < 4; m++) {
#pragma unroll
            for (int r2 = 0; r2 < 4; r2++) {
                int gr = row0 + m * 16 + quad * 4 + r2;
                if (gr < n) {
                    float dv = dinv[gr];
#pragma unroll
                    for (int t = 0; t < 2; t++) {
                        int cj = t * 16 + ln;
                        g1s[((size_t)w * NN + gr) * 32 + cj] = f2bf(acc[m][t][r2] * dv);
                    }
                }
            }
        }
    }
}

// ---------------- agg1: hrb[s][di][32] = bf16(relu(dinv*(sum g1[src]+g1[d]) + b1)) ---
// XCD-resident slices: slice = (blockIdx&7)>>1 -> with round-robin block->XCD dispatch
// each XCD gathers only from its own 3.2 MB (L2-resident) slice of g1s. 4 lanes/dst x
// uint4; side data (row_ptr_p/ssrc_p/dinv_p/hrb) streams in perm order.

__global__ void k_agg1(const ushort* __restrict__ g1s, const float* __restrict__ dinv_p,
                       const int* __restrict__ row_ptr_p, const ushort* __restrict__ ssrc_p,
                       const int* __restrict__ perm, const float* __restrict__ b1,
                       ushort* __restrict__ hrb) {
    int slice = (blockIdx.x & 7) >> 1;               // 4 slices x 2 XCDs
    int dbase = (blockIdx.x >> 3) * 64;
    int wid = threadIdx.x >> 6, lane = threadIdx.x & 63;
    int grp = lane >> 2, fl = lane & 3;              // 16 dst-groups of 4 lanes
    int di = dbase + wid * 16 + grp;
    if (di >= NN) return;
    int d = perm[di];
    const ushort* gs = g1s + (size_t)slice * NN * 32 + fl * 8;
    float a0 = 0.f, a1 = 0.f, a2 = 0.f, a3 = 0.f;
    float a4 = 0.f, a5 = 0.f, a6 = 0.f, a7 = 0.f;
    int e0 = row_ptr_p[di], e1 = row_ptr_p[di + 1];
    if (e1 > e0) {
        int last = e1 - 1;
        int sB0 = ssrc_p[min(e0 + 0, last)];
        int sB1 = ssrc_p[min(e0 + 1, last)];
        int sB2 = ssrc_p[min(e0 + 2, last)];
        int sB3 = ssrc_p[min(e0 + 3, last)];
        uint4 uA0 = *(const uint4*)(gs + (size_t)sB0 * 32);
        uint4 uA1 = *(const uint4*)(gs + (size_t)sB1 * 32);
        uint4 uA2 = *(const uint4*)(gs + (size_t)sB2 * 32);
        uint4 uA3 = *(const uint4*)(gs + (size_t)sB3 * 32);
        sB0 = ssrc_p[min(e0 + 4, last)];
        sB1 = ssrc_p[min(e0 + 5, last)];
        sB2 = ssrc_p[min(e0 + 6, last)];
        sB3 = ssrc_p[min(e0 + 7, last)];
        for (int eb = e0; eb < e1; eb += 4) {
            int p0 = ssrc_p[min(eb + 8, last)];
            int p1 = ssrc_p[min(eb + 9, last)];
            int p2 = ssrc_p[min(eb + 10, last)];
            int p3 = ssrc_p[min(eb + 11, last)];
            uint4 v0 = *(const uint4*)(gs + (size_t)sB0 * 32);
            uint4 v1 = *(const uint4*)(gs + (size_t)sB1 * 32);
            uint4 v2 = *(const uint4*)(gs + (size_t)sB2 * 32);
            uint4 v3 = *(const uint4*)(gs + (size_t)sB3 * 32);
            uint4 z = make_uint4(0u, 0u, 0u, 0u);
            if (eb + 1 >= e1) uA1 = z;
            if (eb + 2 >= e1) uA2 = z;
            if (eb + 3 >= e1) uA3 = z;
            ACC8(uA0); ACC8(uA1); ACC8(uA2); ACC8(uA3);
            uA0 = v0; uA1 = v1; uA2 = v2; uA3 = v3;
            sB0 = p0; sB1 = p1; sB2 = p2; sB3 = p3;
        }
    }
    uint4 ud = *(const uint4*)(gs + (size_t)d * 32);
    ACC8(ud);
    float dv = dinv_p[di];
    const float* bp = b1 + slice * 32 + fl * 8;
    float4 bb0 = *(const float4*)bp;
    float4 bb1 = *(const float4*)(bp + 4);
    uint4 o;
    o.x = pk2(fmaxf(a0 * dv + bb0.x, 0.f), fmaxf(a1 * dv + bb0.y, 0.f));
    o.y = pk2(fmaxf(a2 * dv + bb0.z, 0.f), fmaxf(a3 * dv + bb0.w, 0.f));
    o.z = pk2(fmaxf(a4 * dv + bb1.x, 0.f), fmaxf(a5 * dv + bb1.y, 0.f));
    o.w = pk2(fmaxf(a6 * dv + bb1.z, 0.f), fmaxf(a7 * dv + bb1.w, 0.f));
    *(uint4*)(hrb + ((size_t)slice * NN + di) * 32 + fl * 8) = o;
}

// ---------------- GEMM2 (MFMA bf16): hrb [4][NN][32] perm rows @ W2 -> g2s -----------
// Output g2s [2][NN][32] scattered back to NATURAL order via perm.

__global__ void k_gemm2(const ushort* __restrict__ hrb, const ushort* __restrict__ W2T,
                        const float* __restrict__ dinv_p, const int* __restrict__ perm,
                        ushort* __restrict__ g2s, int n) {
    __shared__ ushort As[64 * 40];
    __shared__ ushort Bs[64 * 40];
    int tid = threadIdx.x;
    int w = tid >> 6, lane = tid & 63;
    int ln = lane & 15, quad = lane >> 4;
    int row0 = blockIdx.x * 64;
    int n0 = w * 16;

    f32x4 acc[4];
#pragma unroll
    for (int m = 0; m < 4; m++) acc[m] = (f32x4){0.f, 0.f, 0.f, 0.f};

    int ar = tid >> 2;
    int ac = (tid & 3) * 8;

    for (int k0 = 0; k0 < HIDIM; k0 += 32) {
        int hs = k0 >> 5;
        {   // stage A from hrb [4][NN][32] (perm-row order)
            int gr = row0 + ar;
            uint4 u = make_uint4(0, 0, 0, 0);
            if (gr < n) u = *(const uint4*)(hrb + ((size_t)hs * NN + gr) * 32 + ac);
            *(uint4*)(As + ar * 40 + ac) = u;
        }
        {   // stage B
            int bn = tid >> 2, bc = (tid & 3) * 8;
            uint4 u = *(const uint4*)(W2T + (size_t)bn * HIDIM + k0 + bc);
            *(uint4*)(Bs + bn * 40 + bc) = u;
        }
        __syncthreads();

        bf16x8 bf = *(const bf16x8*)(Bs + (n0 + ln) * 40 + quad * 8);
#pragma unroll
        for (int m = 0; m < 4; m++) {
            bf16x8 af = *(const bf16x8*)(As + (m * 16 + ln) * 40 + quad * 8);
            acc[m] = __builtin_amdgcn_mfma_f32_16x16x32_bf16(af, bf, acc[m], 0, 0, 0);
        }
        __syncthreads();
    }

    int col = n0 + ln;
    int s2 = col >> 5, cj = col & 31;
#pragma unroll
    for (int m = 0; m < 4; m++) {
#pragma unroll
        for (int r = 0; r < 4; r++) {
            int gr = row0 + m * 16 + quad * 4 + r;
            if (gr < n) {
                int gd = perm[gr];   // back to natural order
                g2s[((size_t)s2 * NN + gd) * 32 + cj] = f2bf(acc[m][r] * dinv_p[gr]);
            }
        }
    }
}

// ---------------- agg2: out[d] = dinv*(sum g2[src] + g2[d]) + b2 ---------------------
// XCD-resident slices: slice = (blockIdx&7)>>2 (2 slices x 4 XCDs, 3.2 MB each).

__global__ void k_agg2(const ushort* __restrict__ g2s, const float* __restrict__ dinv_p,
                       const int* __restrict__ row_ptr_p, const ushort* __restrict__ ssrc_p,
                       const int* __restrict__ perm, const float* __restrict__ b2,
                       float* __restrict__ out) {
    int slice = (blockIdx.x & 7) >> 2;               // 2 slices x 4 XCDs
    int dbase = (blockIdx.x >> 3) * 64;
    int wid = threadIdx.x >> 6, lane = threadIdx.x & 63;
    int grp = lane >> 2, fl = lane & 3;
    int di = dbase + wid * 16 + grp;
    if (di >= NN) return;
    int d = perm[di];
    const ushort* gs = g2s + (size_t)slice * NN * 32 + fl * 8;
    float a0 = 0.f, a1 = 0.f, a2 = 0.f, a3 = 0.f;
    float a4 = 0.f, a5 = 0.f, a6 = 0.f, a7 = 0.f;
    int e0 = row_ptr_p[di], e1 = row_ptr_p[di + 1];
    if (e1 > e0) {
        int last = e1 - 1;
        int sB0 = ssrc_p[min(e0 + 0, last)];
        int sB1 = ssrc_p[min(e0 + 1, last)];
        int sB2 = ssrc_p[min(e0 + 2, last)];
        int sB3 = ssrc_p[min(e0 + 3, last)];
        uint4 uA0 = *(const uint4*)(gs + (size_t)sB0 * 32);
        uint4 uA1 = *(const uint4*)(gs + (size_t)sB1 * 32);
        uint4 uA2 = *(const uint4*)(gs + (size_t)sB2 * 32);
        uint4 uA3 = *(const uint4*)(gs + (size_t)sB3 * 32);
        sB0 = ssrc_p[min(e0 + 4, last)];
        sB1 = ssrc_p[min(e0 + 5, last)];
        sB2 = ssrc_p[min(e0 + 6, last)];
        sB3 = ssrc_p[min(e0 + 7, last)];
        for (int eb = e0; eb < e1; eb += 4) {
            int p0 = ssrc_p[min(eb + 8, last)];
            int p1 = ssrc_p[min(eb + 9, last)];
            int p2 = ssrc_p[min(eb + 10, last)];
            int p3 = ssrc_p[min(eb + 11, last)];
            uint4 v0 = *(const uint4*)(gs + (size_t)sB0 * 32);
            uint4 v1 = *(const uint4*)(gs + (size_t)sB1 * 32);
            uint4 v2 = *(const uint4*)(gs + (size_t)sB2 * 32);
            uint4 v3 = *(const uint4*)(gs + (size_t)sB3 * 32);
            uint4 z = make_uint4(0u, 0u, 0u, 0u);
            if (eb + 1 >= e1) uA1 = z;
            if (eb + 2 >= e1) uA2 = z;
            if (eb + 3 >= e1) uA3 = z;
            ACC8(uA0); ACC8(uA1); ACC8(uA2); ACC8(uA3);
            uA0 = v0; uA1 = v1; uA2 = v2; uA3 = v3;
            sB0 = p0; sB1 = p1; sB2 = p2; sB3 = p3;
        }
    }
    uint4 ud = *(const uint4*)(gs + (size_t)d * 32);
    ACC8(ud);
    float dv = dinv_p[di];
    const float* bp = b2 + slice * 32 + fl * 8;
    float4 bb0 = *(const float4*)bp;
    float4 bb1 = *(const float4*)(bp + 4);
    float4 r0, r1;
    r0.x = a0 * dv + bb0.x;
    r0.y = a1 * dv + bb0.y;
    r0.z = a2 * dv + bb0.z;
    r0.w = a3 * dv + bb0.w;
    r1.x = a4 * dv + bb1.x;
    r1.y = a5 * dv + bb1.y;
    r1.z = a6 * dv + bb1.z;
    r1.w = a7 * dv + bb1.w;
    float* op = out + (size_t)d * OUTDIM + slice * 32 + fl * 8;
    *(float4*)op = r0;
    *(float4*)(op + 4) = r1;
}

// ---------------- launch ----------------

extern "C" void kernel_launch(void* const* d_in, const int* in_sizes, int n_in,
                              void* d_out, int out_size, void* d_ws, size_t ws_size,
                              hipStream_t stream) {
    const float* x   = (const float*)d_in[0];
    const int*   ei  = (const int*)d_in[1];
    const float* W1  = (const float*)d_in[2];
    const float* b1  = (const float*)d_in[3];
    const float* W2  = (const float*)d_in[4];
    const float* b2  = (const float*)d_in[5];
    float* out = (float*)d_out;

    const int* row = ei;        // sources
    const int* col = ei + NE;   // destinations

    size_t off = 0;
    auto alloc = [&](size_t bytes) {
        void* p = (char*)d_ws + off;
        off += (bytes + 255) & ~(size_t)255;
        return p;
    };
    float*  dinv     = (float*) alloc((size_t)NN * 4);
    int*    deg      = (int*)   alloc((size_t)NN * 4);
    int*    rcur     = (int*)   alloc(NRANGE * 4);
    int*    bcnt     = (int*)   alloc((size_t)NRANGE * NBBLK * 4);   // 800 KB
    int*    bbase    = (int*)   alloc((size_t)NRANGE * NBBLK * 4);   // 800 KB
    uint*   staged   = (uint*)  alloc((size_t)NRANGE * ACAP * 4);    // 8 MB
    ushort* ssrc_p   = (ushort*)alloc((size_t)NE * 2);
    ushort* W1T      = (ushort*)alloc((size_t)INDIM * HIDIM * 2);
    ushort* W2T      = (ushort*)alloc((size_t)HIDIM * OUTDIM * 2);
    ushort* g1s      = (ushort*)alloc((size_t)NN * HIDIM * 2);
    ushort* hrb      = (ushort*)alloc((size_t)NN * HIDIM * 2);
    ushort* g2s      = (ushort*)alloc((size_t)NN * OUTDIM * 2);
    int*    perm     = (int*)   alloc((size_t)NN * 4);
    int*    row_ptr_p= (int*)   alloc((size_t)(NN + 1) * 4);
    float*  dinv_p   = (float*) alloc((size_t)NN * 4);

    const int nb64 = (NN + 63) / 64;         // 782

    k_wt<<<(INDIM * HIDIM + HIDIM * OUTDIM + 255) / 256, 256, 0, stream>>>(W1, W2, W1T, W2T, deg);

    k_bcnt<<<NBBLK, 256, 0, stream>>>(col, bcnt, deg);
    k_bscan<<<NRANGE, 1024, 0, stream>>>(bcnt, bbase, rcur, deg, dinv);
    k_bscat<<<NBBLK, 256, 0, stream>>>(row, col, bbase, staged);

    k_sg1<<<NRANGE + NG1, 1024, 0, stream>>>(staged, rcur, dinv_p, row_ptr_p, perm, ssrc_p,
                                             x, W1T, dinv, g1s, NN);

    k_agg1<<<nb64 * 8, 256, 0, stream>>>(g1s, dinv_p, row_ptr_p, ssrc_p, perm, b1, hrb);
    k_gemm2<<<nb64, 256, 0, stream>>>(hrb, W2T, dinv_p, perm, g2s, NN);
    k_agg2<<<nb64 * 8, 256, 0, stream>>>(g2s, dinv_p, row_ptr_p, ssrc_p, perm, b2, out);
}

// Round 9
// 279.431 us; speedup vs baseline: 1.3656x; 1.3656x over previous
//
#include <hip/hip_runtime.h>

#define NN 50000
#define NE 1600000
#define INDIM 256
#define HIDIM 128
#define OUTDIM 64

#define NRANGE 128
#define RSPAN 400             // 125 full ranges (50000 = 125*400), ranges 125..127 empty
#define ACAP 16384            // per-range staging capacity (uint records), +31 sigma
#define NBBLK 1563            // bucket blocks: (NE + 1023) / 1024
#define NDEG 256              // degree histogram bins (Poisson(32): max deg ~70)
#define NG1 196               // gemm1 super-blocks in fused kernel (196*4 = 784 >= 782)

typedef unsigned int uint;
typedef unsigned long long ull;
typedef unsigned short ushort;
typedef __attribute__((ext_vector_type(8))) short bf16x8;
typedef __attribute__((ext_vector_type(4))) float f32x4;

__device__ __forceinline__ ushort f2bf(float f) {
    uint u = __float_as_uint(f);
    uint r = (u + 0x7FFFu + ((u >> 16) & 1u)) >> 16;   // RTNE
    return (ushort)r;
}
__device__ __forceinline__ uint pk2(float a, float b) {
    return (uint)f2bf(a) | ((uint)f2bf(b) << 16);
}
__device__ __forceinline__ float bf_lo(uint u) { return __uint_as_float(u << 16); }
__device__ __forceinline__ float bf_hi(uint u) { return __uint_as_float(u & 0xFFFF0000u); }

// accumulate 8 bf16 features from a uint4
#define ACC8(u) do { \
    a0 += bf_lo((u).x); a1 += bf_hi((u).x); \
    a2 += bf_lo((u).y); a3 += bf_hi((u).y); \
    a4 += bf_lo((u).z); a5 += bf_hi((u).z); \
    a6 += bf_lo((u).w); a7 += bf_hi((u).w); \
} while (0)

// ---------------- weight transpose + bf16 convert; zero deg --------------------------

__global__ void k_wt(const float* __restrict__ W1, const float* __restrict__ W2,
                     ushort* __restrict__ W1T, ushort* __restrict__ W2T,
                     int* __restrict__ deg) {
    int idx = blockIdx.x * 256 + threadIdx.x;
    for (int i = idx; i < NN; i += gridDim.x * 256) deg[i] = 0;
    if (idx < INDIM * HIDIM) {
        int k = idx / HIDIM, nn = idx % HIDIM;
        W1T[nn * INDIM + k] = f2bf(W1[idx]);
    } else {
        int j = idx - INDIM * HIDIM;
        if (j < HIDIM * OUTDIM) {
            int k = j / OUTDIM, nn = j % OUTDIM;
            W2T[nn * HIDIM + k] = f2bf(W2[j]);
        }
    }
}

// ---------------- A1: per-block range counts + global degree count -------------------

__global__ void k_bcnt(const int* __restrict__ col, int* __restrict__ bcnt,
                       int* __restrict__ deg) {
    __shared__ int bins[NRANGE];
    int tid = threadIdx.x;
    if (tid < NRANGE) bins[tid] = 0;
    __syncthreads();
    int base = blockIdx.x * 1024 + tid;
#pragma unroll
    for (int k = 0; k < 4; k++) {
        int i = base + k * 256;
        if (i < NE) {
            int d = col[i];
            atomicAdd(&bins[d / RSPAN], 1);
            atomicAdd(&deg[d], 1);
        }
    }
    __syncthreads();
    if (tid < NRANGE) bcnt[tid * NBBLK + blockIdx.x] = bins[tid];
}

// ---------------- A2: per-range exclusive scan of block counts; dinv from deg --------

__global__ void k_bscan(const int* __restrict__ bcnt, int* __restrict__ bbase,
                        int* __restrict__ rcur, const int* __restrict__ deg,
                        float* __restrict__ dinv) {
    __shared__ int wsum[16];
    __shared__ int woff[16];
    int r = blockIdx.x;
    const int* src = bcnt + r * NBBLK;
    int* dst = bbase + r * NBBLK;
    int tid = threadIdx.x, lane = tid & 63, wid = tid >> 6;
    int gid = r * 1024 + tid;
    if (gid < NN) dinv[gid] = rsqrtf((float)(deg[gid] + 1));   // +1 self loop
    int seg = tid * 2;
    int l0 = (seg < NBBLK) ? src[seg] : 0;
    int l1 = (seg + 1 < NBBLK) ? src[seg + 1] : 0;
    int sum = l0 + l1;
    int incl = sum;
#pragma unroll
    for (int off = 1; off < 64; off <<= 1) {
        int t = __shfl_up(incl, off);
        if (lane >= off) incl += t;
    }
    if (lane == 63) wsum[wid] = incl;
    __syncthreads();
    if (wid == 0 && lane < 16) {
        int wv = wsum[lane];
        int wincl = wv;
#pragma unroll
        for (int off = 1; off < 16; off <<= 1) {
            int t = __shfl_up(wincl, off);
            if (lane >= off) wincl += t;
        }
        woff[lane] = wincl - wv;
    }
    __syncthreads();
    int run = incl - sum + woff[wid];
    if (seg < NBBLK) dst[seg] = run;
    if (seg + 1 < NBBLK) dst[seg + 1] = run + l0;
    if (tid == 1023) rcur[r] = run + sum;
}

// ---------------- A3: block-granular scatter to staged (LDS cursors) -----------------

__global__ void k_bscat(const int* __restrict__ row, const int* __restrict__ col,
                        const int* __restrict__ bbase, uint* __restrict__ staged) {
    __shared__ int cur[NRANGE];
    int tid = threadIdx.x;
    if (tid < NRANGE) cur[tid] = bbase[tid * NBBLK + blockIdx.x];
    __syncthreads();
    int base = blockIdx.x * 1024 + tid;
#pragma unroll
    for (int k = 0; k < 4; k++) {
        int i = base + k * 256;
        if (i < NE) {
            int d = col[i], s = row[i];
            int r = d / RSPAN;
            int off = atomicAdd(&cur[r], 1);
            staged[(size_t)r * ACAP + off] = ((uint)s << 10) | (uint)(d - r * RSPAN);
        }
    }
}

// ---------------- k_sg1: FUSED {counting+degree sort} || {GEMM1} ---------------------
// blocks [0,NRANGE): per-range counting sort + range-local degree sort -> perm-ordered
//   CSR (row_ptr_p, ssrc_p, dinv_p, perm). Sort fills ~half the CUs; gemm1 blocks
//   co-schedule on the rest, hiding sort's serialization.
// blocks [NRANGE, NRANGE+NG1): GEMM1 x[n][256] @ W1 -> g1s [2][NN][64] bf16 (round-7
//   layout), 4 sub-tiles of 64 rows per 1024-thread block, shared Bs stage.

__global__ __launch_bounds__(1024) void k_sg1(
        const uint* __restrict__ staged, const int* __restrict__ rcur,
        float* __restrict__ dinv_p, int* __restrict__ row_ptr_p,
        int* __restrict__ perm, ushort* __restrict__ ssrc_p,
        const float* __restrict__ A, const ushort* __restrict__ W1T,
        const float* __restrict__ dinv, ushort* __restrict__ g1s, int n) {
    __shared__ int bins[RSPAN];
    __shared__ int pdeg[RSPAN];
    __shared__ int prow[RSPAN];
    __shared__ int lperm[RSPAN];
    __shared__ int dh[NDEG];
    __shared__ int wsum[16];
    __shared__ int woff[16];
    __shared__ ushort As[4 * 64 * 40];
    __shared__ ushort Bs[128 * 40];

    int tid = threadIdx.x, lane = tid & 63, wid = tid >> 6;

    if (blockIdx.x < NRANGE) {
        // ---------------- sort path ----------------
        int r = blockIdx.x;
        int lo = r * RSPAN;
        int count = rcur[r];
        int rbase = 0;
        for (int rr = 0; rr < r; rr++) rbase += rcur[rr];
        if (lo >= NN) {                              // empty tail ranges (125..127)
            if (lo == NN && tid == 0) row_ptr_p[NN] = rbase;   // rbase == NE here
            return;
        }
        const uint* st = staged + (size_t)r * ACAP;

        if (tid < RSPAN) bins[tid] = 0;
        if (tid < NDEG) dh[tid] = 0;
        __syncthreads();

        // pass 1: count per-node degree
        for (int i = tid; i < count; i += 1024)
            atomicAdd(&bins[st[i] & 1023u], 1);
        __syncthreads();

        int deg = (tid < RSPAN) ? bins[tid] : 0;
        bool valid = tid < RSPAN;                    // non-empty ranges are exactly full
        if (valid) atomicAdd(&dh[min(deg, NDEG - 1)], 1);
        __syncthreads();

        // exclusive scan of dh[256] by wave 0 (4 bins/lane) -> class bases (in place)
        if (wid == 0) {
            int b = lane * 4;
            int v0 = dh[b], v1 = dh[b + 1], v2 = dh[b + 2], v3 = dh[b + 3];
            int s = v0 + v1 + v2 + v3;
            int incl = s;
#pragma unroll
            for (int off = 1; off < 64; off <<= 1) {
                int t = __shfl_up(incl, off);
                if (lane >= off) incl += t;
            }
            int excl = incl - s;
            dh[b] = excl;
            dh[b + 1] = excl + v0;
            dh[b + 2] = excl + v0 + v1;
            dh[b + 3] = excl + v0 + v1 + v2;
        }
        __syncthreads();

        // local perm rank (atomic ticket within degree class)
        int rl = 0;
        if (valid) rl = atomicAdd(&dh[min(deg, NDEG - 1)], 1);
        if (valid) { pdeg[rl] = deg; lperm[rl] = tid; }
        __syncthreads();

        // exclusive scan of pdeg[RSPAN] -> prow
        int v = (tid < RSPAN) ? pdeg[tid] : 0;
        int incl = v;
#pragma unroll
        for (int off = 1; off < 64; off <<= 1) {
            int t = __shfl_up(incl, off);
            if (lane >= off) incl += t;
        }
        if (lane == 63) wsum[wid] = incl;
        __syncthreads();
        if (wid == 0 && lane < 16) {
            int wv = wsum[lane];
            int wincl = wv;
#pragma unroll
            for (int off = 1; off < 16; off <<= 1) {
                int t = __shfl_up(wincl, off);
                if (lane >= off) wincl += t;
            }
            woff[lane] = wincl - wv;
        }
        __syncthreads();
        int excl = incl - v + woff[wid];
        if (tid < RSPAN) prow[tid] = excl;
        __syncthreads();

        // permuted CSR metadata (streaming writes)
        if (tid < RSPAN) {
            int di = lo + tid;
            row_ptr_p[di] = rbase + prow[tid];
            perm[di] = lo + lperm[tid];
            dinv_p[di] = rsqrtf((float)(pdeg[tid] + 1));
        }
        __syncthreads();
        if (valid) bins[tid] = rbase + prow[rl];     // pass-2 cursors by dloc
        __syncthreads();

        // pass 2: scatter to exact perm-ordered CSR slots
        for (int i = tid; i < count; i += 1024) {
            uint rec = st[i];
            int pos = atomicAdd(&bins[rec & 1023u], 1);
            ssrc_p[pos] = (ushort)(rec >> 10);
        }
    } else {
        // ---------------- gemm1 path: 4 x 64-row tiles, shared Bs ----------------
        int sub = blockIdx.x - NRANGE;
        int g = tid >> 8;                 // sub-group 0..3
        int t256 = tid & 255;
        int w = t256 >> 6;
        int l256 = t256 & 63;
        int ln = l256 & 15, quad = l256 >> 4;
        int row0 = (sub * 4 + g) * 64;
        int n0 = w * 32;
        ushort* Asg = As + g * (64 * 40);

        f32x4 acc[4][2];
#pragma unroll
        for (int m = 0; m < 4; m++)
#pragma unroll
            for (int t = 0; t < 2; t++) acc[m][t] = (f32x4){0.f, 0.f, 0.f, 0.f};

        int ar = t256 >> 2;
        int ac = (t256 & 3) * 8;

        for (int k0 = 0; k0 < INDIM; k0 += 32) {
            {   // stage A: 64 rows x 32 k per sub-group, f32 -> bf16
                int gr = row0 + ar;
                uint4 u = make_uint4(0, 0, 0, 0);
                if (gr < n) {
                    const float* p = A + (size_t)gr * INDIM + k0 + ac;
                    float4 v0 = *(const float4*)p;
                    float4 v1 = *(const float4*)(p + 4);
                    u.x = pk2(v0.x, v0.y); u.y = pk2(v0.z, v0.w);
                    u.z = pk2(v1.x, v1.y); u.w = pk2(v1.z, v1.w);
                }
                *(uint4*)(Asg + ar * 40 + ac) = u;
            }
            if (tid < 512) {   // stage B once for all 4 sub-tiles: 128 rows x 32 k
                int bn = tid >> 2, bc = (tid & 3) * 8;
                uint4 u = *(const uint4*)(W1T + (size_t)bn * INDIM + k0 + bc);
                *(uint4*)(Bs + bn * 40 + bc) = u;
            }
            __syncthreads();

            bf16x8 af[4], bf[2];
#pragma unroll
            for (int m = 0; m < 4; m++)
                af[m] = *(const bf16x8*)(Asg + (m * 16 + ln) * 40 + quad * 8);
#pragma unroll
            for (int t = 0; t < 2; t++)
                bf[t] = *(const bf16x8*)(Bs + (n0 + t * 16 + ln) * 40 + quad * 8);
#pragma unroll
            for (int m = 0; m < 4; m++)
#pragma unroll
                for (int t = 0; t < 2; t++)
                    acc[m][t] = __builtin_amdgcn_mfma_f32_16x16x32_bf16(af[m], bf[t], acc[m][t], 0, 0, 0);
            __syncthreads();
        }

        // epilogue: round-7 layout g1s [2][NN][64]; slice = w>>1, fbase = (w&1)*32
        int slice = w >> 1;
        int fbase = (w & 1) * 32;
#pragma unroll
        for (int m = 0; m < 4; m++) {
#pragma unroll
            for (int r2 = 0; r2 < 4; r2++) {
                int gr = row0 + m * 16 + quad * 4 + r2;
                if (gr < n) {
                    float dv = dinv[gr];
#pragma unroll
                    for (int t = 0; t < 2; t++) {
                        int cj = t * 16 + ln;
                        g1s[((size_t)slice * NN + gr) * 64 + fbase + cj] = f2bf(acc[m][t][r2] * dv);
                    }
                }
            }
        }
    }
}

// ---------------- agg1: hrb[s][di][64] = bf16(relu(dinv*(sum g1[src]+g1[d]) + b1)) ---
// Round-7 structure: di in perm order, 8 lanes/dst x uint4 over 128B rows; side data
// streams; gathers natural-order (cache-absorbed). Two-deep pipeline.

__global__ void k_agg1(const ushort* __restrict__ g1s, const float* __restrict__ dinv_p,
                       const int* __restrict__ row_ptr_p, const ushort* __restrict__ ssrc_p,
                       const int* __restrict__ perm, const float* __restrict__ b1,
                       ushort* __restrict__ hrb) {
    int slice = blockIdx.x & 1;
    int dbase = (blockIdx.x >> 1) * 32;
    int wid = threadIdx.x >> 6, lane = threadIdx.x & 63;
    int grp = lane >> 3, fl = lane & 7;
    int di = dbase + wid * 8 + grp;
    if (di >= NN) return;
    int d = perm[di];
    const ushort* gs = g1s + (size_t)slice * NN * 64 + fl * 8;
    float a0 = 0.f, a1 = 0.f, a2 = 0.f, a3 = 0.f;
    float a4 = 0.f, a5 = 0.f, a6 = 0.f, a7 = 0.f;
    int e0 = row_ptr_p[di], e1 = row_ptr_p[di + 1];
    if (e1 > e0) {
        int last = e1 - 1;
        int sB0 = ssrc_p[min(e0 + 0, last)];
        int sB1 = ssrc_p[min(e0 + 1, last)];
        int sB2 = ssrc_p[min(e0 + 2, last)];
        int sB3 = ssrc_p[min(e0 + 3, last)];
        uint4 uA0 = *(const uint4*)(gs + (size_t)sB0 * 64);
        uint4 uA1 = *(const uint4*)(gs + (size_t)sB1 * 64);
        uint4 uA2 = *(const uint4*)(gs + (size_t)sB2 * 64);
        uint4 uA3 = *(const uint4*)(gs + (size_t)sB3 * 64);
        sB0 = ssrc_p[min(e0 + 4, last)];
        sB1 = ssrc_p[min(e0 + 5, last)];
        sB2 = ssrc_p[min(e0 + 6, last)];
        sB3 = ssrc_p[min(e0 + 7, last)];
        for (int eb = e0; eb < e1; eb += 4) {
            int p0 = ssrc_p[min(eb + 8, last)];
            int p1 = ssrc_p[min(eb + 9, last)];
            int p2 = ssrc_p[min(eb + 10, last)];
            int p3 = ssrc_p[min(eb + 11, last)];
            uint4 v0 = *(const uint4*)(gs + (size_t)sB0 * 64);
            uint4 v1 = *(const uint4*)(gs + (size_t)sB1 * 64);
            uint4 v2 = *(const uint4*)(gs + (size_t)sB2 * 64);
            uint4 v3 = *(const uint4*)(gs + (size_t)sB3 * 64);
            uint4 z = make_uint4(0u, 0u, 0u, 0u);
            if (eb + 1 >= e1) uA1 = z;
            if (eb + 2 >= e1) uA2 = z;
            if (eb + 3 >= e1) uA3 = z;
            ACC8(uA0); ACC8(uA1); ACC8(uA2); ACC8(uA3);
            uA0 = v0; uA1 = v1; uA2 = v2; uA3 = v3;
            sB0 = p0; sB1 = p1; sB2 = p2; sB3 = p3;
        }
    }
    uint4 ud = *(const uint4*)(gs + (size_t)d * 64);
    ACC8(ud);
    float dv = dinv_p[di];
    const float* bp = b1 + slice * 64 + fl * 8;
    float4 bb0 = *(const float4*)bp;
    float4 bb1 = *(const float4*)(bp + 4);
    uint4 o;
    o.x = pk2(fmaxf(a0 * dv + bb0.x, 0.f), fmaxf(a1 * dv + bb0.y, 0.f));
    o.y = pk2(fmaxf(a2 * dv + bb0.z, 0.f), fmaxf(a3 * dv + bb0.w, 0.f));
    o.z = pk2(fmaxf(a4 * dv + bb1.x, 0.f), fmaxf(a5 * dv + bb1.y, 0.f));
    o.w = pk2(fmaxf(a6 * dv + bb1.z, 0.f), fmaxf(a7 * dv + bb1.w, 0.f));
    *(uint4*)(hrb + ((size_t)slice * NN + di) * 64 + fl * 8) = o;
}

// ---------------- GEMM2 (MFMA bf16): hrb(perm rows) @ W2 -> g2s [NN][64] natural -----

__global__ void k_gemm2(const ushort* __restrict__ hrb, const ushort* __restrict__ W2T,
                        const float* __restrict__ dinv_p, const int* __restrict__ perm,
                        ushort* __restrict__ g2s, int n) {
    __shared__ ushort As[64 * 40];
    __shared__ ushort Bs[64 * 40];
    int tid = threadIdx.x;
    int w = tid >> 6, lane = tid & 63;
    int ln = lane & 15, quad = lane >> 4;
    int row0 = blockIdx.x * 64;
    int n0 = w * 16;

    f32x4 acc[4];
#pragma unroll
    for (int m = 0; m < 4; m++) acc[m] = (f32x4){0.f, 0.f, 0.f, 0.f};

    int ar = tid >> 2;
    int ac = (tid & 3) * 8;

    for (int k0 = 0; k0 < HIDIM; k0 += 32) {
        {   // stage A from hrb [2][NN][64] (perm-row order)
            int gr = row0 + ar;
            uint4 u = make_uint4(0, 0, 0, 0);
            if (gr < n) u = *(const uint4*)(hrb + ((size_t)(k0 >> 6) * NN + gr) * 64 + (k0 & 63) + ac);
            *(uint4*)(As + ar * 40 + ac) = u;
        }
        {   // stage B
            int bn = tid >> 2, bc = (tid & 3) * 8;
            uint4 u = *(const uint4*)(W2T + (size_t)bn * HIDIM + k0 + bc);
            *(uint4*)(Bs + bn * 40 + bc) = u;
        }
        __syncthreads();

        bf16x8 bf = *(const bf16x8*)(Bs + (n0 + ln) * 40 + quad * 8);
#pragma unroll
        for (int m = 0; m < 4; m++) {
            bf16x8 af = *(const bf16x8*)(As + (m * 16 + ln) * 40 + quad * 8);
            acc[m] = __builtin_amdgcn_mfma_f32_16x16x32_bf16(af, bf, acc[m], 0, 0, 0);
        }
        __syncthreads();
    }

    int col = n0 + ln;
#pragma unroll
    for (int m = 0; m < 4; m++) {
#pragma unroll
        for (int r = 0; r < 4; r++) {
            int gr = row0 + m * 16 + quad * 4 + r;
            if (gr < n) {
                int gd = perm[gr];   // scatter back to natural order (full 128B rows)
                g2s[(size_t)gd * 64 + col] = f2bf(acc[m][r] * dinv_p[gr]);
            }
        }
    }
}

// ---------------- agg2: out[d][64] = dinv*(sum g2[src] + g2[d]) + b2 -----------------
// Round-7 structure: single pass, 8 lanes/dst, full 256B out rows.

__global__ void k_agg2(const ushort* __restrict__ g2s, const float* __restrict__ dinv_p,
                       const int* __restrict__ row_ptr_p, const ushort* __restrict__ ssrc_p,
                       const int* __restrict__ perm, const float* __restrict__ b2,
                       float* __restrict__ out) {
    int dbase = blockIdx.x * 32;
    int wid = threadIdx.x >> 6, lane = threadIdx.x & 63;
    int grp = lane >> 3, fl = lane & 7;
    int di = dbase + wid * 8 + grp;
    if (di >= NN) return;
    int d = perm[di];
    const ushort* gs = g2s + fl * 8;
    float a0 = 0.f, a1 = 0.f, a2 = 0.f, a3 = 0.f;
    float a4 = 0.f, a5 = 0.f, a6 = 0.f, a7 = 0.f;
    int e0 = row_ptr_p[di], e1 = row_ptr_p[di + 1];
    if (e1 > e0) {
        int last = e1 - 1;
        int sB0 = ssrc_p[min(e0 + 0, last)];
        int sB1 = ssrc_p[min(e0 + 1, last)];
        int sB2 = ssrc_p[min(e0 + 2, last)];
        int sB3 = ssrc_p[min(e0 + 3, last)];
        uint4 uA0 = *(const uint4*)(gs + (size_t)sB0 * 64);
        uint4 uA1 = *(const uint4*)(gs + (size_t)sB1 * 64);
        uint4 uA2 = *(const uint4*)(gs + (size_t)sB2 * 64);
        uint4 uA3 = *(const uint4*)(gs + (size_t)sB3 * 64);
        sB0 = ssrc_p[min(e0 + 4, last)];
        sB1 = ssrc_p[min(e0 + 5, last)];
        sB2 = ssrc_p[min(e0 + 6, last)];
        sB3 = ssrc_p[min(e0 + 7, last)];
        for (int eb = e0; eb < e1; eb += 4) {
            int p0 = ssrc_p[min(eb + 8, last)];
            int p1 = ssrc_p[min(eb + 9, last)];
            int p2 = ssrc_p[min(eb + 10, last)];
            int p3 = ssrc_p[min(eb + 11, last)];
            uint4 v0 = *(const uint4*)(gs + (size_t)sB0 * 64);
            uint4 v1 = *(const uint4*)(gs + (size_t)sB1 * 64);
            uint4 v2 = *(const uint4*)(gs + (size_t)sB2 * 64);
            uint4 v3 = *(const uint4*)(gs + (size_t)sB3 * 64);
            uint4 z = make_uint4(0u, 0u, 0u, 0u);
            if (eb + 1 >= e1) uA1 = z;
            if (eb + 2 >= e1) uA2 = z;
            if (eb + 3 >= e1) uA3 = z;
            ACC8(uA0); ACC8(uA1); ACC8(uA2); ACC8(uA3);
            uA0 = v0; uA1 = v1; uA2 = v2; uA3 = v3;
            sB0 = p0; sB1 = p1; sB2 = p2; sB3 = p3;
        }
    }
    uint4 ud = *(const uint4*)(gs + (size_t)d * 64);
    ACC8(ud);
    float dv = dinv_p[di];
    const float* bp = b2 + fl * 8;
    float4 bb0 = *(const float4*)bp;
    float4 bb1 = *(const float4*)(bp + 4);
    float4 r0, r1;
    r0.x = a0 * dv + bb0.x;
    r0.y = a1 * dv + bb0.y;
    r0.z = a2 * dv + bb0.z;
    r0.w = a3 * dv + bb0.w;
    r1.x = a4 * dv + bb1.x;
    r1.y = a5 * dv + bb1.y;
    r1.z = a6 * dv + bb1.z;
    r1.w = a7 * dv + bb1.w;
    float* op = out + (size_t)d * OUTDIM + fl * 8;
    *(float4*)op = r0;
    *(float4*)(op + 4) = r1;
}

// ---------------- launch ----------------

extern "C" void kernel_launch(void* const* d_in, const int* in_sizes, int n_in,
                              void* d_out, int out_size, void* d_ws, size_t ws_size,
                              hipStream_t stream) {
    const float* x   = (const float*)d_in[0];
    const int*   ei  = (const int*)d_in[1];
    const float* W1  = (const float*)d_in[2];
    const float* b1  = (const float*)d_in[3];
    const float* W2  = (const float*)d_in[4];
    const float* b2  = (const float*)d_in[5];
    float* out = (float*)d_out;

    const int* row = ei;        // sources
    const int* col = ei + NE;   // destinations

    size_t off = 0;
    auto alloc = [&](size_t bytes) {
        void* p = (char*)d_ws + off;
        off += (bytes + 255) & ~(size_t)255;
        return p;
    };
    float*  dinv     = (float*) alloc((size_t)NN * 4);
    int*    deg      = (int*)   alloc((size_t)NN * 4);
    int*    rcur     = (int*)   alloc(NRANGE * 4);
    int*    bcnt     = (int*)   alloc((size_t)NRANGE * NBBLK * 4);   // 800 KB
    int*    bbase    = (int*)   alloc((size_t)NRANGE * NBBLK * 4);   // 800 KB
    uint*   staged   = (uint*)  alloc((size_t)NRANGE * ACAP * 4);    // 8 MB
    ushort* ssrc_p   = (ushort*)alloc((size_t)NE * 2);
    ushort* W1T      = (ushort*)alloc((size_t)INDIM * HIDIM * 2);
    ushort* W2T      = (ushort*)alloc((size_t)HIDIM * OUTDIM * 2);
    ushort* g1s      = (ushort*)alloc((size_t)NN * HIDIM * 2);
    ushort* hrb      = (ushort*)alloc((size_t)NN * HIDIM * 2);
    ushort* g2s      = (ushort*)alloc((size_t)NN * OUTDIM * 2);
    int*    perm     = (int*)   alloc((size_t)NN * 4);
    int*    row_ptr_p= (int*)   alloc((size_t)(NN + 1) * 4);
    float*  dinv_p   = (float*) alloc((size_t)NN * 4);

    const int nb32 = (NN + 31) / 32;         // 1563
    const int nb64 = (NN + 63) / 64;         // 782

    k_wt<<<(INDIM * HIDIM + HIDIM * OUTDIM + 255) / 256, 256, 0, stream>>>(W1, W2, W1T, W2T, deg);

    k_bcnt<<<NBBLK, 256, 0, stream>>>(col, bcnt, deg);
    k_bscan<<<NRANGE, 1024, 0, stream>>>(bcnt, bbase, rcur, deg, dinv);
    k_bscat<<<NBBLK, 256, 0, stream>>>(row, col, bbase, staged);

    k_sg1<<<NRANGE + NG1, 1024, 0, stream>>>(staged, rcur, dinv_p, row_ptr_p, perm, ssrc_p,
                                             x, W1T, dinv, g1s, NN);

    k_agg1<<<nb32 * 2, 256, 0, stream>>>(g1s, dinv_p, row_ptr_p, ssrc_p, perm, b1, hrb);
    k_gemm2<<<nb64, 256, 0, stream>>>(hrb, W2T, dinv_p, perm, g2s, NN);
    k_agg2<<<nb32, 256, 0, stream>>>(g2s, dinv_p, row_ptr_p, ssrc_p, perm, b2, out);
}

// Round 10
// 222.030 us; speedup vs baseline: 1.7186x; 1.2585x over previous
//
#include <hip/hip_runtime.h>

#define NN 50000
#define NE 1600000
#define INDIM 256
#define HIDIM 128
#define OUTDIM 64

#define NRANGE 256
#define RSPAN 200             // 250 full ranges (50000 = 250*200), ranges 250..255 empty
#define ACAP 8192             // per-range staging capacity (uint records), +22 sigma
#define NBBLK 1563            // bucket blocks: (NE + 1023) / 1024
#define NDEG 256              // degree histogram bins (Poisson(32): max deg ~70)

typedef unsigned int uint;
typedef unsigned long long ull;
typedef unsigned short ushort;
typedef __attribute__((ext_vector_type(8))) short bf16x8;
typedef __attribute__((ext_vector_type(4))) float f32x4;

__device__ __forceinline__ ushort f2bf(float f) {
    uint u = __float_as_uint(f);
    uint r = (u + 0x7FFFu + ((u >> 16) & 1u)) >> 16;   // RTNE
    return (ushort)r;
}
__device__ __forceinline__ uint pk2(float a, float b) {
    return (uint)f2bf(a) | ((uint)f2bf(b) << 16);
}
__device__ __forceinline__ float bf_lo(uint u) { return __uint_as_float(u << 16); }
__device__ __forceinline__ float bf_hi(uint u) { return __uint_as_float(u & 0xFFFF0000u); }

// accumulate 8 bf16 features from a uint4
#define ACC8(u) do { \
    a0 += bf_lo((u).x); a1 += bf_hi((u).x); \
    a2 += bf_lo((u).y); a3 += bf_hi((u).y); \
    a4 += bf_lo((u).z); a5 += bf_hi((u).z); \
    a6 += bf_lo((u).w); a7 += bf_hi((u).w); \
} while (0)

// ---------------- weight transpose + bf16 convert (fused) ----------------

__global__ void k_wt(const float* __restrict__ W1, const float* __restrict__ W2,
                     ushort* __restrict__ W1T, ushort* __restrict__ W2T) {
    int idx = blockIdx.x * 256 + threadIdx.x;
    if (idx < INDIM * HIDIM) {
        int k = idx / HIDIM, nn = idx % HIDIM;
        W1T[nn * INDIM + k] = f2bf(W1[idx]);
    } else {
        int j = idx - INDIM * HIDIM;
        if (j < HIDIM * OUTDIM) {
            int k = j / OUTDIM, nn = j % OUTDIM;
            W2T[nn * HIDIM + k] = f2bf(W2[j]);
        }
    }
}

// ---------------- A1: per-block range counts via LDS bins ----------------------------

__global__ void k_bcnt(const int* __restrict__ col, int* __restrict__ bcnt) {
    __shared__ int bins[NRANGE];
    int tid = threadIdx.x;
    if (tid < NRANGE) bins[tid] = 0;
    __syncthreads();
    int base = blockIdx.x * 1024 + tid;
#pragma unroll
    for (int k = 0; k < 4; k++) {
        int i = base + k * 256;
        if (i < NE) atomicAdd(&bins[col[i] / RSPAN], 1);
    }
    __syncthreads();
    if (tid < NRANGE) bcnt[tid * NBBLK + blockIdx.x] = bins[tid];
}

// ---------------- A2: per-range exclusive scan of block counts -----------------------

__global__ void k_bscan(const int* __restrict__ bcnt, int* __restrict__ bbase,
                        int* __restrict__ rcur) {
    __shared__ int wsum[16];
    __shared__ int woff[16];
    int r = blockIdx.x;
    const int* src = bcnt + r * NBBLK;
    int* dst = bbase + r * NBBLK;
    int tid = threadIdx.x, lane = tid & 63, wid = tid >> 6;
    int seg = tid * 2;
    int l0 = (seg < NBBLK) ? src[seg] : 0;
    int l1 = (seg + 1 < NBBLK) ? src[seg + 1] : 0;
    int sum = l0 + l1;
    int incl = sum;
#pragma unroll
    for (int off = 1; off < 64; off <<= 1) {
        int t = __shfl_up(incl, off);
        if (lane >= off) incl += t;
    }
    if (lane == 63) wsum[wid] = incl;
    __syncthreads();
    if (wid == 0 && lane < 16) {
        int wv = wsum[lane];
        int wincl = wv;
#pragma unroll
        for (int off = 1; off < 16; off <<= 1) {
            int t = __shfl_up(wincl, off);
            if (lane >= off) wincl += t;
        }
        woff[lane] = wincl - wv;
    }
    __syncthreads();
    int run = incl - sum + woff[wid];
    if (seg < NBBLK) dst[seg] = run;
    if (seg + 1 < NBBLK) dst[seg + 1] = run + l0;
    if (tid == 1023) rcur[r] = run + sum;
}

// ---------------- A3: block-granular scatter to staged (LDS cursors) -----------------
// Record: (s << 8) | dloc  (dloc < 200 fits 8 bits, s < 50000 fits 16 bits).

__global__ void k_bscat(const int* __restrict__ row, const int* __restrict__ col,
                        const int* __restrict__ bbase, uint* __restrict__ staged) {
    __shared__ int cur[NRANGE];
    int tid = threadIdx.x;
    if (tid < NRANGE) cur[tid] = bbase[tid * NBBLK + blockIdx.x];
    __syncthreads();
    int base = blockIdx.x * 1024 + tid;
#pragma unroll
    for (int k = 0; k < 4; k++) {
        int i = base + k * 256;
        if (i < NE) {
            int d = col[i], s = row[i];
            int r = d / RSPAN;
            int off = atomicAdd(&cur[r], 1);
            staged[(size_t)r * ACAP + off] = ((uint)s << 8) | (uint)(d - r * RSPAN);
        }
    }
}

// ---------------- k_sort: counting sort + RANGE-LOCAL degree sort, fused -------------
// 256 blocks (one per range) -> full-device parallelism. Per range: count degrees ->
// local degree-histogram sort (perm within range) -> closed-form permuted CSR
// (row_ptr_p via scan of permuted degrees) -> scatter records directly into
// perm-ordered CSR slots. Emits dinv (natural), perm, dinv_p, row_ptr_p, ssrc_p.

__global__ void k_sort(const uint* __restrict__ staged, const int* __restrict__ rcur,
                       float* __restrict__ dinv, float* __restrict__ dinv_p,
                       int* __restrict__ row_ptr_p, int* __restrict__ perm,
                       ushort* __restrict__ ssrc_p) {
    __shared__ int bins[RSPAN];     // counts -> pass-2 cursors
    __shared__ int pdeg[RSPAN];     // degree of perm-ordered node j
    __shared__ int prow[RSPAN];     // local exclusive row starts (perm order)
    __shared__ int lperm[RSPAN];    // local perm: j -> dloc
    __shared__ int dh[NDEG];        // degree histogram -> class cursors
    __shared__ int wsum[16];
    __shared__ int woff[16];
    int r = blockIdx.x;
    int tid = threadIdx.x, lane = tid & 63, wid = tid >> 6;
    int lo = r * RSPAN;
    int count = rcur[r];
    int rbase = 0;
    for (int rr = 0; rr < r; rr++) rbase += rcur[rr];
    if (lo >= NN) {                              // empty tail ranges (250..255)
        if (lo == NN && tid == 0) row_ptr_p[NN] = rbase;   // rbase == NE here
        return;
    }
    const uint* st = staged + (size_t)r * ACAP;

    if (tid < RSPAN) bins[tid] = 0;
    if (tid < NDEG) dh[tid] = 0;
    __syncthreads();

    // pass 1: count per-node degree
    for (int i = tid; i < count; i += 1024)
        atomicAdd(&bins[st[i] & 255u], 1);
    __syncthreads();

    int deg = (tid < RSPAN) ? bins[tid] : 0;
    bool valid = tid < RSPAN;                    // non-empty ranges are exactly full
    if (valid) {
        dinv[lo + tid] = rsqrtf((float)(deg + 1));   // natural order (gemm1 epilogue)
        atomicAdd(&dh[min(deg, NDEG - 1)], 1);
    }
    __syncthreads();

    // exclusive scan of dh[256] by wave 0 (4 bins/lane) -> class bases (in place)
    if (wid == 0) {
        int b = lane * 4;
        int v0 = dh[b], v1 = dh[b + 1], v2 = dh[b + 2], v3 = dh[b + 3];
        int s = v0 + v1 + v2 + v3;
        int incl = s;
#pragma unroll
        for (int off = 1; off < 64; off <<= 1) {
            int t = __shfl_up(incl, off);
            if (lane >= off) incl += t;
        }
        int excl = incl - s;
        dh[b] = excl;
        dh[b + 1] = excl + v0;
        dh[b + 2] = excl + v0 + v1;
        dh[b + 3] = excl + v0 + v1 + v2;
    }
    __syncthreads();

    // local perm rank (atomic ticket within degree class)
    int rl = 0;
    if (valid) rl = atomicAdd(&dh[min(deg, NDEG - 1)], 1);
    if (valid) { pdeg[rl] = deg; lperm[rl] = tid; }
    __syncthreads();

    // exclusive scan of pdeg[RSPAN] -> prow (local row starts in perm order)
    int v = (tid < RSPAN) ? pdeg[tid] : 0;
    int incl = v;
#pragma unroll
    for (int off = 1; off < 64; off <<= 1) {
        int t = __shfl_up(incl, off);
        if (lane >= off) incl += t;
    }
    if (lane == 63) wsum[wid] = incl;
    __syncthreads();
    if (wid == 0 && lane < 16) {
        int wv = wsum[lane];
        int wincl = wv;
#pragma unroll
        for (int off = 1; off < 16; off <<= 1) {
            int t = __shfl_up(wincl, off);
            if (lane >= off) wincl += t;
        }
        woff[lane] = wincl - wv;
    }
    __syncthreads();
    int excl = incl - v + woff[wid];
    if (tid < RSPAN) prow[tid] = excl;
    __syncthreads();

    // permuted CSR metadata (all streaming writes)
    if (tid < RSPAN) {
        int di = lo + tid;
        row_ptr_p[di] = rbase + prow[tid];
        perm[di] = lo + lperm[tid];
        dinv_p[di] = rsqrtf((float)(pdeg[tid] + 1));
    }
    __syncthreads();
    if (valid) bins[tid] = rbase + prow[rl];     // pass-2 cursors by dloc
    __syncthreads();

    // pass 2: scatter to exact perm-ordered CSR slots (dense within range window)
    for (int i = tid; i < count; i += 1024) {
        uint rec = st[i];
        int pos = atomicAdd(&bins[rec & 255u], 1);
        ssrc_p[pos] = (ushort)(rec >> 8);
    }
}

// ---------------- GEMM1 (MFMA bf16): x[n][256] @ W1 -> g1s [2][NN][64] bf16 ----------

__global__ void k_gemm1(const float* __restrict__ A, const ushort* __restrict__ W1T,
                        const float* __restrict__ dinv, ushort* __restrict__ g1s, int n) {
    __shared__ ushort As[64 * 40];
    __shared__ ushort Bs[128 * 40];
    int tid = threadIdx.x;
    int w = tid >> 6, lane = tid & 63;
    int ln = lane & 15, quad = lane >> 4;
    int row0 = blockIdx.x * 64;
    int n0 = w * 32;

    f32x4 acc[4][2];
#pragma unroll
    for (int m = 0; m < 4; m++)
#pragma unroll
        for (int t = 0; t < 2; t++) acc[m][t] = (f32x4){0.f, 0.f, 0.f, 0.f};

    int ar = tid >> 2;
    int ac = (tid & 3) * 8;

    for (int k0 = 0; k0 < INDIM; k0 += 32) {
        {   // stage A: 64 rows x 32 k, f32 -> bf16
            int gr = row0 + ar;
            uint4 u = make_uint4(0, 0, 0, 0);
            if (gr < n) {
                const float* p = A + (size_t)gr * INDIM + k0 + ac;
                float4 v0 = *(const float4*)p;
                float4 v1 = *(const float4*)(p + 4);
                u.x = pk2(v0.x, v0.y); u.y = pk2(v0.z, v0.w);
                u.z = pk2(v1.x, v1.y); u.w = pk2(v1.z, v1.w);
            }
            *(uint4*)(As + ar * 40 + ac) = u;
        }
#pragma unroll
        for (int it = 0; it < 2; it++) {   // stage B: 128 rows x 32 k
            int idx = tid + it * 256;
            int bn = idx >> 2, bc = (idx & 3) * 8;
            uint4 u = *(const uint4*)(W1T + (size_t)bn * INDIM + k0 + bc);
            *(uint4*)(Bs + bn * 40 + bc) = u;
        }
        __syncthreads();

        bf16x8 af[4], bf[2];
#pragma unroll
        for (int m = 0; m < 4; m++)
            af[m] = *(const bf16x8*)(As + (m * 16 + ln) * 40 + quad * 8);
#pragma unroll
        for (int t = 0; t < 2; t++)
            bf[t] = *(const bf16x8*)(Bs + (n0 + t * 16 + ln) * 40 + quad * 8);
#pragma unroll
        for (int m = 0; m < 4; m++)
#pragma unroll
            for (int t = 0; t < 2; t++)
                acc[m][t] = __builtin_amdgcn_mfma_f32_16x16x32_bf16(af[m], bf[t], acc[m][t], 0, 0, 0);
        __syncthreads();
    }

    int slice = w >> 1;
    int fbase = (w & 1) * 32;
#pragma unroll
    for (int m = 0; m < 4; m++) {
#pragma unroll
        for (int r = 0; r < 4; r++) {
            int gr = row0 + m * 16 + quad * 4 + r;
            if (gr < n) {
                float dv = dinv[gr];
#pragma unroll
                for (int t = 0; t < 2; t++) {
                    int cj = t * 16 + ln;
                    g1s[((size_t)slice * NN + gr) * 64 + fbase + cj] = f2bf(acc[m][t][r] * dv);
                }
            }
        }
    }
}

// ---------------- agg1: hrb[s][di][64] = bf16(relu(dinv*(sum g1[src]+g1[d]) + b1)) ---
// di iterates perm order: row_ptr_p / ssrc_p / dinv_p / hrb all sequential; only the
// g1s gathers (cache-absorbed) + one self-row are random. Two-deep pipeline, 8 lanes/dst.

__global__ void k_agg1(const ushort* __restrict__ g1s, const float* __restrict__ dinv_p,
                       const int* __restrict__ row_ptr_p, const ushort* __restrict__ ssrc_p,
                       const int* __restrict__ perm, const float* __restrict__ b1,
                       ushort* __restrict__ hrb) {
    int slice = blockIdx.x & 1;
    int dbase = (blockIdx.x >> 1) * 32;
    int wid = threadIdx.x >> 6, lane = threadIdx.x & 63;
    int grp = lane >> 3, fl = lane & 7;
    int di = dbase + wid * 8 + grp;
    if (di >= NN) return;
    int d = perm[di];
    const ushort* gs = g1s + (size_t)slice * NN * 64 + fl * 8;
    float a0 = 0.f, a1 = 0.f, a2 = 0.f, a3 = 0.f;
    float a4 = 0.f, a5 = 0.f, a6 = 0.f, a7 = 0.f;
    int e0 = row_ptr_p[di], e1 = row_ptr_p[di + 1];
    if (e1 > e0) {
        int last = e1 - 1;
        int sB0 = ssrc_p[min(e0 + 0, last)];
        int sB1 = ssrc_p[min(e0 + 1, last)];
        int sB2 = ssrc_p[min(e0 + 2, last)];
        int sB3 = ssrc_p[min(e0 + 3, last)];
        uint4 uA0 = *(const uint4*)(gs + (size_t)sB0 * 64);
        uint4 uA1 = *(const uint4*)(gs + (size_t)sB1 * 64);
        uint4 uA2 = *(const uint4*)(gs + (size_t)sB2 * 64);
        uint4 uA3 = *(const uint4*)(gs + (size_t)sB3 * 64);
        sB0 = ssrc_p[min(e0 + 4, last)];
        sB1 = ssrc_p[min(e0 + 5, last)];
        sB2 = ssrc_p[min(e0 + 6, last)];
        sB3 = ssrc_p[min(e0 + 7, last)];
        for (int eb = e0; eb < e1; eb += 4) {
            int p0 = ssrc_p[min(eb + 8, last)];
            int p1 = ssrc_p[min(eb + 9, last)];
            int p2 = ssrc_p[min(eb + 10, last)];
            int p3 = ssrc_p[min(eb + 11, last)];
            uint4 v0 = *(const uint4*)(gs + (size_t)sB0 * 64);
            uint4 v1 = *(const uint4*)(gs + (size_t)sB1 * 64);
            uint4 v2 = *(const uint4*)(gs + (size_t)sB2 * 64);
            uint4 v3 = *(const uint4*)(gs + (size_t)sB3 * 64);
            uint4 z = make_uint4(0u, 0u, 0u, 0u);
            if (eb + 1 >= e1) uA1 = z;
            if (eb + 2 >= e1) uA2 = z;
            if (eb + 3 >= e1) uA3 = z;
            ACC8(uA0); ACC8(uA1); ACC8(uA2); ACC8(uA3);
            uA0 = v0; uA1 = v1; uA2 = v2; uA3 = v3;
            sB0 = p0; sB1 = p1; sB2 = p2; sB3 = p3;
        }
    }
    uint4 ud = *(const uint4*)(gs + (size_t)d * 64);
    ACC8(ud);
    float dv = dinv_p[di];
    const float* bp = b1 + slice * 64 + fl * 8;
    float4 bb0 = *(const float4*)bp;
    float4 bb1 = *(const float4*)(bp + 4);
    uint4 o;
    o.x = pk2(fmaxf(a0 * dv + bb0.x, 0.f), fmaxf(a1 * dv + bb0.y, 0.f));
    o.y = pk2(fmaxf(a2 * dv + bb0.z, 0.f), fmaxf(a3 * dv + bb0.w, 0.f));
    o.z = pk2(fmaxf(a4 * dv + bb1.x, 0.f), fmaxf(a5 * dv + bb1.y, 0.f));
    o.w = pk2(fmaxf(a6 * dv + bb1.z, 0.f), fmaxf(a7 * dv + bb1.w, 0.f));
    *(uint4*)(hrb + ((size_t)slice * NN + di) * 64 + fl * 8) = o;
}

// ---------------- GEMM2 (MFMA bf16): hrb(perm rows) @ W2 -> g2s [NN][64] natural -----

__global__ void k_gemm2(const ushort* __restrict__ hrb, const ushort* __restrict__ W2T,
                        const float* __restrict__ dinv_p, const int* __restrict__ perm,
                        ushort* __restrict__ g2s, int n) {
    __shared__ ushort As[64 * 40];
    __shared__ ushort Bs[64 * 40];
    int tid = threadIdx.x;
    int w = tid >> 6, lane = tid & 63;
    int ln = lane & 15, quad = lane >> 4;
    int row0 = blockIdx.x * 64;
    int n0 = w * 16;

    f32x4 acc[4];
#pragma unroll
    for (int m = 0; m < 4; m++) acc[m] = (f32x4){0.f, 0.f, 0.f, 0.f};

    int ar = tid >> 2;
    int ac = (tid & 3) * 8;

    for (int k0 = 0; k0 < HIDIM; k0 += 32) {
        {   // stage A from hrb [2][NN][64] (perm-row order)
            int gr = row0 + ar;
            uint4 u = make_uint4(0, 0, 0, 0);
            if (gr < n) u = *(const uint4*)(hrb + ((size_t)(k0 >> 6) * NN + gr) * 64 + (k0 & 63) + ac);
            *(uint4*)(As + ar * 40 + ac) = u;
        }
        {   // stage B
            int bn = tid >> 2, bc = (tid & 3) * 8;
            uint4 u = *(const uint4*)(W2T + (size_t)bn * HIDIM + k0 + bc);
            *(uint4*)(Bs + bn * 40 + bc) = u;
        }
        __syncthreads();

        bf16x8 bf = *(const bf16x8*)(Bs + (n0 + ln) * 40 + quad * 8);
#pragma unroll
        for (int m = 0; m < 4; m++) {
            bf16x8 af = *(const bf16x8*)(As + (m * 16 + ln) * 40 + quad * 8);
            acc[m] = __builtin_amdgcn_mfma_f32_16x16x32_bf16(af, bf, acc[m], 0, 0, 0);
        }
        __syncthreads();
    }

    int col = n0 + ln;
#pragma unroll
    for (int m = 0; m < 4; m++) {
#pragma unroll
        for (int r = 0; r < 4; r++) {
            int gr = row0 + m * 16 + quad * 4 + r;
            if (gr < n) {
                int gd = perm[gr];   // scatter back to natural order (full 128B rows)
                g2s[(size_t)gd * 64 + col] = f2bf(acc[m][r] * dinv_p[gr]);
            }
        }
    }
}

// ---------------- agg2: out[d][64] = dinv*(sum g2[src] + g2[d]) + b2 -----------------
// Same perm-sequential structure; final out write scattered (256B rows, once).

__global__ void k_agg2(const ushort* __restrict__ g2s, const float* __restrict__ dinv_p,
                       const int* __restrict__ row_ptr_p, const ushort* __restrict__ ssrc_p,
                       const int* __restrict__ perm, const float* __restrict__ b2,
                       float* __restrict__ out) {
    int dbase = blockIdx.x * 32;
    int wid = threadIdx.x >> 6, lane = threadIdx.x & 63;
    int grp = lane >> 3, fl = lane & 7;
    int di = dbase + wid * 8 + grp;
    if (di >= NN) return;
    int d = perm[di];
    const ushort* gs = g2s + fl * 8;
    float a0 = 0.f, a1 = 0.f, a2 = 0.f, a3 = 0.f;
    float a4 = 0.f, a5 = 0.f, a6 = 0.f, a7 = 0.f;
    int e0 = row_ptr_p[di], e1 = row_ptr_p[di + 1];
    if (e1 > e0) {
        int last = e1 - 1;
        int sB0 = ssrc_p[min(e0 + 0, last)];
        int sB1 = ssrc_p[min(e0 + 1, last)];
        int sB2 = ssrc_p[min(e0 + 2, last)];
        int sB3 = ssrc_p[min(e0 + 3, last)];
        uint4 uA0 = *(const uint4*)(gs + (size_t)sB0 * 64);
        uint4 uA1 = *(const uint4*)(gs + (size_t)sB1 * 64);
        uint4 uA2 = *(const uint4*)(gs + (size_t)sB2 * 64);
        uint4 uA3 = *(const uint4*)(gs + (size_t)sB3 * 64);
        sB0 = ssrc_p[min(e0 + 4, last)];
        sB1 = ssrc_p[min(e0 + 5, last)];
        sB2 = ssrc_p[min(e0 + 6, last)];
        sB3 = ssrc_p[min(e0 + 7, last)];
        for (int eb = e0; eb < e1; eb += 4) {
            int p0 = ssrc_p[min(eb + 8, last)];
            int p1 = ssrc_p[min(eb + 9, last)];
            int p2 = ssrc_p[min(eb + 10, last)];
            int p3 = ssrc_p[min(eb + 11, last)];
            uint4 v0 = *(const uint4*)(gs + (size_t)sB0 * 64);
            uint4 v1 = *(const uint4*)(gs + (size_t)sB1 * 64);
            uint4 v2 = *(const uint4*)(gs + (size_t)sB2 * 64);
            uint4 v3 = *(const uint4*)(gs + (size_t)sB3 * 64);
            uint4 z = make_uint4(0u, 0u, 0u, 0u);
            if (eb + 1 >= e1) uA1 = z;
            if (eb + 2 >= e1) uA2 = z;
            if (eb + 3 >= e1) uA3 = z;
            ACC8(uA0); ACC8(uA1); ACC8(uA2); ACC8(uA3);
            uA0 = v0; uA1 = v1; uA2 = v2; uA3 = v3;
            sB0 = p0; sB1 = p1; sB2 = p2; sB3 = p3;
        }
    }
    uint4 ud = *(const uint4*)(gs + (size_t)d * 64);
    ACC8(ud);
    float dv = dinv_p[di];
    const float* bp = b2 + fl * 8;
    float4 bb0 = *(const float4*)bp;
    float4 bb1 = *(const float4*)(bp + 4);
    float4 r0, r1;
    r0.x = a0 * dv + bb0.x;
    r0.y = a1 * dv + bb0.y;
    r0.z = a2 * dv + bb0.z;
    r0.w = a3 * dv + bb0.w;
    r1.x = a4 * dv + bb1.x;
    r1.y = a5 * dv + bb1.y;
    r1.z = a6 * dv + bb1.z;
    r1.w = a7 * dv + bb1.w;
    float* op = out + (size_t)d * OUTDIM + fl * 8;
    *(float4*)op = r0;
    *(float4*)(op + 4) = r1;
}

// ---------------- launch ----------------

extern "C" void kernel_launch(void* const* d_in, const int* in_sizes, int n_in,
                              void* d_out, int out_size, void* d_ws, size_t ws_size,
                              hipStream_t stream) {
    const float* x   = (const float*)d_in[0];
    const int*   ei  = (const int*)d_in[1];
    const float* W1  = (const float*)d_in[2];
    const float* b1  = (const float*)d_in[3];
    const float* W2  = (const float*)d_in[4];
    const float* b2  = (const float*)d_in[5];
    float* out = (float*)d_out;

    const int* row = ei;        // sources
    const int* col = ei + NE;   // destinations

    size_t off = 0;
    auto alloc = [&](size_t bytes) {
        void* p = (char*)d_ws + off;
        off += (bytes + 255) & ~(size_t)255;
        return p;
    };
    float*  dinv     = (float*) alloc((size_t)NN * 4);
    int*    rcur     = (int*)   alloc(NRANGE * 4);
    int*    bcnt     = (int*)   alloc((size_t)NRANGE * NBBLK * 4);   // 1.6 MB
    int*    bbase    = (int*)   alloc((size_t)NRANGE * NBBLK * 4);   // 1.6 MB
    uint*   staged   = (uint*)  alloc((size_t)NRANGE * ACAP * 4);    // 8 MB
    ushort* ssrc_p   = (ushort*)alloc((size_t)NE * 2);
    ushort* W1T      = (ushort*)alloc((size_t)INDIM * HIDIM * 2);
    ushort* W2T      = (ushort*)alloc((size_t)HIDIM * OUTDIM * 2);
    ushort* g1s      = (ushort*)alloc((size_t)NN * HIDIM * 2);
    ushort* hrb      = (ushort*)alloc((size_t)NN * HIDIM * 2);
    ushort* g2s      = (ushort*)alloc((size_t)NN * OUTDIM * 2);
    int*    perm     = (int*)   alloc((size_t)NN * 4);
    int*    row_ptr_p= (int*)   alloc((size_t)(NN + 1) * 4);
    float*  dinv_p   = (float*) alloc((size_t)NN * 4);

    const int nb32 = (NN + 31) / 32;         // 1563
    const int nb64 = (NN + 63) / 64;         // 782

    k_wt<<<(INDIM * HIDIM + HIDIM * OUTDIM + 255) / 256, 256, 0, stream>>>(W1, W2, W1T, W2T);

    k_bcnt<<<NBBLK, 256, 0, stream>>>(col, bcnt);
    k_bscan<<<NRANGE, 1024, 0, stream>>>(bcnt, bbase, rcur);
    k_bscat<<<NBBLK, 256, 0, stream>>>(row, col, bbase, staged);

    k_sort<<<NRANGE, 1024, 0, stream>>>(staged, rcur, dinv, dinv_p, row_ptr_p, perm, ssrc_p);

    k_gemm1<<<nb64, 256, 0, stream>>>(x, W1T, dinv, g1s, NN);
    k_agg1<<<nb32 * 2, 256, 0, stream>>>(g1s, dinv_p, row_ptr_p, ssrc_p, perm, b1, hrb);
    k_gemm2<<<nb64, 256, 0, stream>>>(hrb, W2T, dinv_p, perm, g2s, NN);
    k_agg2<<<nb32, 256, 0, stream>>>(g2s, dinv_p, row_ptr_p, ssrc_p, perm, b2, out);
}

// Round 11
// 216.403 us; speedup vs baseline: 1.7633x; 1.0260x over previous
//
#include <hip/hip_runtime.h>

#define NN 50000
#define NE 1600000
#define INDIM 256
#define HIDIM 128
#define OUTDIM 64

#define NRANGE 128
#define RSPAN 400             // 125 full ranges (50000 = 125*400), ranges 125..127 empty
#define ACAP 16384            // per-range staging capacity (uint records), +31 sigma
#define NBBLK 1563            // bucket blocks: (NE + 1023) / 1024
#define NDEG 256              // degree histogram bins (Poisson(32): max deg ~70)

typedef unsigned int uint;
typedef unsigned long long ull;
typedef unsigned short ushort;
typedef __attribute__((ext_vector_type(8))) short bf16x8;
typedef __attribute__((ext_vector_type(4))) float f32x4;

__device__ __forceinline__ ushort f2bf(float f) {
    uint u = __float_as_uint(f);
    uint r = (u + 0x7FFFu + ((u >> 16) & 1u)) >> 16;   // RTNE
    return (ushort)r;
}
__device__ __forceinline__ uint pk2(float a, float b) {
    return (uint)f2bf(a) | ((uint)f2bf(b) << 16);
}
__device__ __forceinline__ float bf_lo(uint u) { return __uint_as_float(u << 16); }
__device__ __forceinline__ float bf_hi(uint u) { return __uint_as_float(u & 0xFFFF0000u); }

// accumulate 8 bf16 features from a uint4
#define ACC8(u) do { \
    a0 += bf_lo((u).x); a1 += bf_hi((u).x); \
    a2 += bf_lo((u).y); a3 += bf_hi((u).y); \
    a4 += bf_lo((u).z); a5 += bf_hi((u).z); \
    a6 += bf_lo((u).w); a7 += bf_hi((u).w); \
} while (0)

// ---------------- weight transpose + bf16 convert (fused) ----------------

__global__ void k_wt(const float* __restrict__ W1, const float* __restrict__ W2,
                     ushort* __restrict__ W1T, ushort* __restrict__ W2T) {
    int idx = blockIdx.x * 256 + threadIdx.x;
    if (idx < INDIM * HIDIM) {
        int k = idx / HIDIM, nn = idx % HIDIM;
        W1T[nn * INDIM + k] = f2bf(W1[idx]);
    } else {
        int j = idx - INDIM * HIDIM;
        if (j < HIDIM * OUTDIM) {
            int k = j / OUTDIM, nn = j % OUTDIM;
            W2T[nn * HIDIM + k] = f2bf(W2[j]);
        }
    }
}

// ---------------- A1: per-block range counts via LDS bins ----------------------------

__global__ void k_bcnt(const int* __restrict__ col, int* __restrict__ bcnt) {
    __shared__ int bins[NRANGE];
    int tid = threadIdx.x;
    if (tid < NRANGE) bins[tid] = 0;
    __syncthreads();
    int base = blockIdx.x * 1024 + tid;
#pragma unroll
    for (int k = 0; k < 4; k++) {
        int i = base + k * 256;
        if (i < NE) atomicAdd(&bins[col[i] / RSPAN], 1);
    }
    __syncthreads();
    if (tid < NRANGE) bcnt[tid * NBBLK + blockIdx.x] = bins[tid];
}

// ---------------- A2: per-range exclusive scan of block counts -----------------------

__global__ void k_bscan(const int* __restrict__ bcnt, int* __restrict__ bbase,
                        int* __restrict__ rcur) {
    __shared__ int wsum[16];
    __shared__ int woff[16];
    int r = blockIdx.x;
    const int* src = bcnt + r * NBBLK;
    int* dst = bbase + r * NBBLK;
    int tid = threadIdx.x, lane = tid & 63, wid = tid >> 6;
    int seg = tid * 2;
    int l0 = (seg < NBBLK) ? src[seg] : 0;
    int l1 = (seg + 1 < NBBLK) ? src[seg + 1] : 0;
    int sum = l0 + l1;
    int incl = sum;
#pragma unroll
    for (int off = 1; off < 64; off <<= 1) {
        int t = __shfl_up(incl, off);
        if (lane >= off) incl += t;
    }
    if (lane == 63) wsum[wid] = incl;
    __syncthreads();
    if (wid == 0 && lane < 16) {
        int wv = wsum[lane];
        int wincl = wv;
#pragma unroll
        for (int off = 1; off < 16; off <<= 1) {
            int t = __shfl_up(wincl, off);
            if (lane >= off) wincl += t;
        }
        woff[lane] = wincl - wv;
    }
    __syncthreads();
    int run = incl - sum + woff[wid];
    if (seg < NBBLK) dst[seg] = run;
    if (seg + 1 < NBBLK) dst[seg + 1] = run + l0;
    if (tid == 1023) rcur[r] = run + sum;
}

// ---------------- A3: block-granular scatter to staged (LDS cursors) -----------------

__global__ void k_bscat(const int* __restrict__ row, const int* __restrict__ col,
                        const int* __restrict__ bbase, uint* __restrict__ staged) {
    __shared__ int cur[NRANGE];
    int tid = threadIdx.x;
    if (tid < NRANGE) cur[tid] = bbase[tid * NBBLK + blockIdx.x];
    __syncthreads();
    int base = blockIdx.x * 1024 + tid;
#pragma unroll
    for (int k = 0; k < 4; k++) {
        int i = base + k * 256;
        if (i < NE) {
            int d = col[i], s = row[i];
            int r = d / RSPAN;
            int off = atomicAdd(&cur[r], 1);
            staged[(size_t)r * ACAP + off] = ((uint)s << 10) | (uint)(d - r * RSPAN);
        }
    }
}

// ---------------- k_sort: counting sort + RANGE-LOCAL degree sort, fused -------------
// Per range: count degrees -> local degree-histogram sort (perm within range) ->
// closed-form permuted CSR (row_ptr_p via scan of permuted degrees) -> scatter records
// directly into perm-ordered CSR slots (writes dense in the range's output window).
// Emits: dinv (natural, for gemm1), perm, dinv_p, row_ptr_p, ssrc_p. No extra kernels.

__global__ void k_sort(const uint* __restrict__ staged, const int* __restrict__ rcur,
                       float* __restrict__ dinv, float* __restrict__ dinv_p,
                       int* __restrict__ row_ptr_p, int* __restrict__ perm,
                       ushort* __restrict__ ssrc_p) {
    __shared__ int bins[RSPAN];     // counts -> pass-2 cursors
    __shared__ int pdeg[RSPAN];     // degree of perm-ordered node j
    __shared__ int prow[RSPAN];     // local exclusive row starts (perm order)
    __shared__ int lperm[RSPAN];    // local perm: j -> dloc
    __shared__ int dh[NDEG];        // degree histogram -> class cursors
    __shared__ int wsum[16];
    __shared__ int woff[16];
    int r = blockIdx.x;
    int tid = threadIdx.x, lane = tid & 63, wid = tid >> 6;
    int lo = r * RSPAN;
    int count = rcur[r];
    int rbase = 0;
    for (int rr = 0; rr < r; rr++) rbase += rcur[rr];
    if (lo >= NN) {                              // empty tail ranges (125..127)
        if (lo == NN && tid == 0) row_ptr_p[NN] = rbase;   // rbase == NE here
        return;
    }
    const uint* st = staged + (size_t)r * ACAP;

    if (tid < RSPAN) bins[tid] = 0;
    if (tid < NDEG) dh[tid] = 0;
    __syncthreads();

    // pass 1: count per-node degree
    for (int i = tid; i < count; i += 1024)
        atomicAdd(&bins[st[i] & 1023u], 1);
    __syncthreads();

    int deg = (tid < RSPAN) ? bins[tid] : 0;
    bool valid = tid < RSPAN;                    // non-empty ranges are exactly full
    if (valid) {
        dinv[lo + tid] = rsqrtf((float)(deg + 1));   // natural order (gemm1 epilogue)
        atomicAdd(&dh[min(deg, NDEG - 1)], 1);
    }
    __syncthreads();

    // exclusive scan of dh[256] by wave 0 (4 bins/lane) -> class bases (in place)
    if (wid == 0) {
        int b = lane * 4;
        int v0 = dh[b], v1 = dh[b + 1], v2 = dh[b + 2], v3 = dh[b + 3];
        int s = v0 + v1 + v2 + v3;
        int incl = s;
#pragma unroll
        for (int off = 1; off < 64; off <<= 1) {
            int t = __shfl_up(incl, off);
            if (lane >= off) incl += t;
        }
        int excl = incl - s;
        dh[b] = excl;
        dh[b + 1] = excl + v0;
        dh[b + 2] = excl + v0 + v1;
        dh[b + 3] = excl + v0 + v1 + v2;
    }
    __syncthreads();

    // local perm rank (stable within degree class via atomic ticket)
    int rl = 0;
    if (valid) rl = atomicAdd(&dh[min(deg, NDEG - 1)], 1);
    if (valid) { pdeg[rl] = deg; lperm[rl] = tid; }
    __syncthreads();

    // exclusive scan of pdeg[RSPAN] -> prow (local row starts in perm order)
    int v = (tid < RSPAN) ? pdeg[tid] : 0;
    int incl = v;
#pragma unroll
    for (int off = 1; off < 64; off <<= 1) {
        int t = __shfl_up(incl, off);
        if (lane >= off) incl += t;
    }
    if (lane == 63) wsum[wid] = incl;
    __syncthreads();
    if (wid == 0 && lane < 16) {
        int wv = wsum[lane];
        int wincl = wv;
#pragma unroll
        for (int off = 1; off < 16; off <<= 1) {
            int t = __shfl_up(wincl, off);
            if (lane >= off) wincl += t;
        }
        woff[lane] = wincl - wv;
    }
    __syncthreads();
    int excl = incl - v + woff[wid];
    if (tid < RSPAN) prow[tid] = excl;
    __syncthreads();

    // permuted CSR metadata (all streaming writes)
    if (tid < RSPAN) {
        int di = lo + tid;
        row_ptr_p[di] = rbase + prow[tid];
        perm[di] = lo + lperm[tid];
        dinv_p[di] = rsqrtf((float)(pdeg[tid] + 1));
    }
    __syncthreads();
    // pass-2 cursors indexed by dloc: start of this node's perm-ordered segment
    if (valid) bins[tid] = rbase + prow[rl];
    __syncthreads();

    // pass 2: scatter to exact perm-ordered CSR slots (dense within range window)
    for (int i = tid; i < count; i += 1024) {
        uint rec = st[i];
        int pos = atomicAdd(&bins[rec & 1023u], 1);
        ssrc_p[pos] = (ushort)(rec >> 10);
    }
}

// ---------------- GEMM1 (MFMA bf16): x[n][256] @ W1 -> g1s [2][NN][64] bf16 ----------

__global__ void k_gemm1(const float* __restrict__ A, const ushort* __restrict__ W1T,
                        const float* __restrict__ dinv, ushort* __restrict__ g1s, int n) {
    __shared__ ushort As[64 * 40];
    __shared__ ushort Bs[128 * 40];
    int tid = threadIdx.x;
    int w = tid >> 6, lane = tid & 63;
    int ln = lane & 15, quad = lane >> 4;
    int row0 = blockIdx.x * 64;
    int n0 = w * 32;

    f32x4 acc[4][2];
#pragma unroll
    for (int m = 0; m < 4; m++)
#pragma unroll
        for (int t = 0; t < 2; t++) acc[m][t] = (f32x4){0.f, 0.f, 0.f, 0.f};

    int ar = tid >> 2;
    int ac = (tid & 3) * 8;

    for (int k0 = 0; k0 < INDIM; k0 += 32) {
        {   // stage A: 64 rows x 32 k, f32 -> bf16
            int gr = row0 + ar;
            uint4 u = make_uint4(0, 0, 0, 0);
            if (gr < n) {
                const float* p = A + (size_t)gr * INDIM + k0 + ac;
                float4 v0 = *(const float4*)p;
                float4 v1 = *(const float4*)(p + 4);
                u.x = pk2(v0.x, v0.y); u.y = pk2(v0.z, v0.w);
                u.z = pk2(v1.x, v1.y); u.w = pk2(v1.z, v1.w);
            }
            *(uint4*)(As + ar * 40 + ac) = u;
        }
#pragma unroll
        for (int it = 0; it < 2; it++) {   // stage B: 128 rows x 32 k
            int idx = tid + it * 256;
            int bn = idx >> 2, bc = (idx & 3) * 8;
            uint4 u = *(const uint4*)(W1T + (size_t)bn * INDIM + k0 + bc);
            *(uint4*)(Bs + bn * 40 + bc) = u;
        }
        __syncthreads();

        bf16x8 af[4], bf[2];
#pragma unroll
        for (int m = 0; m < 4; m++)
            af[m] = *(const bf16x8*)(As + (m * 16 + ln) * 40 + quad * 8);
#pragma unroll
        for (int t = 0; t < 2; t++)
            bf[t] = *(const bf16x8*)(Bs + (n0 + t * 16 + ln) * 40 + quad * 8);
#pragma unroll
        for (int m = 0; m < 4; m++)
#pragma unroll
            for (int t = 0; t < 2; t++)
                acc[m][t] = __builtin_amdgcn_mfma_f32_16x16x32_bf16(af[m], bf[t], acc[m][t], 0, 0, 0);
        __syncthreads();
    }

    int slice = w >> 1;
    int fbase = (w & 1) * 32;
#pragma unroll
    for (int m = 0; m < 4; m++) {
#pragma unroll
        for (int r = 0; r < 4; r++) {
            int gr = row0 + m * 16 + quad * 4 + r;
            if (gr < n) {
                float dv = dinv[gr];
#pragma unroll
                for (int t = 0; t < 2; t++) {
                    int cj = t * 16 + ln;
                    g1s[((size_t)slice * NN + gr) * 64 + fbase + cj] = f2bf(acc[m][t][r] * dv);
                }
            }
        }
    }
}

// ---------------- agg1: hrb[s][di][64] = bf16(relu(dinv*(sum g1[src]+g1[d]) + b1)) ---
// di iterates perm order: row_ptr_p / ssrc_p / dinv_p / hrb all sequential; only the
// g1s gathers (cache-absorbed) + one self-row are random. Two-deep pipeline, 8 lanes/dst.

__global__ void k_agg1(const ushort* __restrict__ g1s, const float* __restrict__ dinv_p,
                       const int* __restrict__ row_ptr_p, const ushort* __restrict__ ssrc_p,
                       const int* __restrict__ perm, const float* __restrict__ b1,
                       ushort* __restrict__ hrb) {
    int slice = blockIdx.x & 1;
    int dbase = (blockIdx.x >> 1) * 32;
    int wid = threadIdx.x >> 6, lane = threadIdx.x & 63;
    int grp = lane >> 3, fl = lane & 7;
    int di = dbase + wid * 8 + grp;
    if (di >= NN) return;
    int d = perm[di];
    const ushort* gs = g1s + (size_t)slice * NN * 64 + fl * 8;
    float a0 = 0.f, a1 = 0.f, a2 = 0.f, a3 = 0.f;
    float a4 = 0.f, a5 = 0.f, a6 = 0.f, a7 = 0.f;
    int e0 = row_ptr_p[di], e1 = row_ptr_p[di + 1];
    if (e1 > e0) {
        int last = e1 - 1;
        int sB0 = ssrc_p[min(e0 + 0, last)];
        int sB1 = ssrc_p[min(e0 + 1, last)];
        int sB2 = ssrc_p[min(e0 + 2, last)];
        int sB3 = ssrc_p[min(e0 + 3, last)];
        uint4 uA0 = *(const uint4*)(gs + (size_t)sB0 * 64);
        uint4 uA1 = *(const uint4*)(gs + (size_t)sB1 * 64);
        uint4 uA2 = *(const uint4*)(gs + (size_t)sB2 * 64);
        uint4 uA3 = *(const uint4*)(gs + (size_t)sB3 * 64);
        sB0 = ssrc_p[min(e0 + 4, last)];
        sB1 = ssrc_p[min(e0 + 5, last)];
        sB2 = ssrc_p[min(e0 + 6, last)];
        sB3 = ssrc_p[min(e0 + 7, last)];
        for (int eb = e0; eb < e1; eb += 4) {
            int p0 = ssrc_p[min(eb + 8, last)];
            int p1 = ssrc_p[min(eb + 9, last)];
            int p2 = ssrc_p[min(eb + 10, last)];
            int p3 = ssrc_p[min(eb + 11, last)];
            uint4 v0 = *(const uint4*)(gs + (size_t)sB0 * 64);
            uint4 v1 = *(const uint4*)(gs + (size_t)sB1 * 64);
            uint4 v2 = *(const uint4*)(gs + (size_t)sB2 * 64);
            uint4 v3 = *(const uint4*)(gs + (size_t)sB3 * 64);
            uint4 z = make_uint4(0u, 0u, 0u, 0u);
            if (eb + 1 >= e1) uA1 = z;
            if (eb + 2 >= e1) uA2 = z;
            if (eb + 3 >= e1) uA3 = z;
            ACC8(uA0); ACC8(uA1); ACC8(uA2); ACC8(uA3);
            uA0 = v0; uA1 = v1; uA2 = v2; uA3 = v3;
            sB0 = p0; sB1 = p1; sB2 = p2; sB3 = p3;
        }
    }
    uint4 ud = *(const uint4*)(gs + (size_t)d * 64);
    ACC8(ud);
    float dv = dinv_p[di];
    const float* bp = b1 + slice * 64 + fl * 8;
    float4 bb0 = *(const float4*)bp;
    float4 bb1 = *(const float4*)(bp + 4);
    uint4 o;
    o.x = pk2(fmaxf(a0 * dv + bb0.x, 0.f), fmaxf(a1 * dv + bb0.y, 0.f));
    o.y = pk2(fmaxf(a2 * dv + bb0.z, 0.f), fmaxf(a3 * dv + bb0.w, 0.f));
    o.z = pk2(fmaxf(a4 * dv + bb1.x, 0.f), fmaxf(a5 * dv + bb1.y, 0.f));
    o.w = pk2(fmaxf(a6 * dv + bb1.z, 0.f), fmaxf(a7 * dv + bb1.w, 0.f));
    *(uint4*)(hrb + ((size_t)slice * NN + di) * 64 + fl * 8) = o;
}

// ---------------- GEMM2 (MFMA bf16): hrb(perm rows) @ W2 -> g2s [NN][64] natural -----

__global__ void k_gemm2(const ushort* __restrict__ hrb, const ushort* __restrict__ W2T,
                        const float* __restrict__ dinv_p, const int* __restrict__ perm,
                        ushort* __restrict__ g2s, int n) {
    __shared__ ushort As[64 * 40];
    __shared__ ushort Bs[64 * 40];
    int tid = threadIdx.x;
    int w = tid >> 6, lane = tid & 63;
    int ln = lane & 15, quad = lane >> 4;
    int row0 = blockIdx.x * 64;
    int n0 = w * 16;

    f32x4 acc[4];
#pragma unroll
    for (int m = 0; m < 4; m++) acc[m] = (f32x4){0.f, 0.f, 0.f, 0.f};

    int ar = tid >> 2;
    int ac = (tid & 3) * 8;

    for (int k0 = 0; k0 < HIDIM; k0 += 32) {
        {   // stage A from hrb [2][NN][64] (perm-row order)
            int gr = row0 + ar;
            uint4 u = make_uint4(0, 0, 0, 0);
            if (gr < n) u = *(const uint4*)(hrb + ((size_t)(k0 >> 6) * NN + gr) * 64 + (k0 & 63) + ac);
            *(uint4*)(As + ar * 40 + ac) = u;
        }
        {   // stage B
            int bn = tid >> 2, bc = (tid & 3) * 8;
            uint4 u = *(const uint4*)(W2T + (size_t)bn * HIDIM + k0 + bc);
            *(uint4*)(Bs + bn * 40 + bc) = u;
        }
        __syncthreads();

        bf16x8 bf = *(const bf16x8*)(Bs + (n0 + ln) * 40 + quad * 8);
#pragma unroll
        for (int m = 0; m < 4; m++) {
            bf16x8 af = *(const bf16x8*)(As + (m * 16 + ln) * 40 + quad * 8);
            acc[m] = __builtin_amdgcn_mfma_f32_16x16x32_bf16(af, bf, acc[m], 0, 0, 0);
        }
        __syncthreads();
    }

    int col = n0 + ln;
#pragma unroll
    for (int m = 0; m < 4; m++) {
#pragma unroll
        for (int r = 0; r < 4; r++) {
            int gr = row0 + m * 16 + quad * 4 + r;
            if (gr < n) {
                int gd = perm[gr];   // scatter back to natural order (full 128B rows)
                g2s[(size_t)gd * 64 + col] = f2bf(acc[m][r] * dinv_p[gr]);
            }
        }
    }
}

// ---------------- agg2: out[d][64] = dinv*(sum g2[src] + g2[d]) + b2 -----------------
// Same perm-sequential structure; final out write scattered (256B rows, once).

__global__ void k_agg2(const ushort* __restrict__ g2s, const float* __restrict__ dinv_p,
                       const int* __restrict__ row_ptr_p, const ushort* __restrict__ ssrc_p,
                       const int* __restrict__ perm, const float* __restrict__ b2,
                       float* __restrict__ out) {
    int dbase = blockIdx.x * 32;
    int wid = threadIdx.x >> 6, lane = threadIdx.x & 63;
    int grp = lane >> 3, fl = lane & 7;
    int di = dbase + wid * 8 + grp;
    if (di >= NN) return;
    int d = perm[di];
    const ushort* gs = g2s + fl * 8;
    float a0 = 0.f, a1 = 0.f, a2 = 0.f, a3 = 0.f;
    float a4 = 0.f, a5 = 0.f, a6 = 0.f, a7 = 0.f;
    int e0 = row_ptr_p[di], e1 = row_ptr_p[di + 1];
    if (e1 > e0) {
        int last = e1 - 1;
        int sB0 = ssrc_p[min(e0 + 0, last)];
        int sB1 = ssrc_p[min(e0 + 1, last)];
        int sB2 = ssrc_p[min(e0 + 2, last)];
        int sB3 = ssrc_p[min(e0 + 3, last)];
        uint4 uA0 = *(const uint4*)(gs + (size_t)sB0 * 64);
        uint4 uA1 = *(const uint4*)(gs + (size_t)sB1 * 64);
        uint4 uA2 = *(const uint4*)(gs + (size_t)sB2 * 64);
        uint4 uA3 = *(const uint4*)(gs + (size_t)sB3 * 64);
        sB0 = ssrc_p[min(e0 + 4, last)];
        sB1 = ssrc_p[min(e0 + 5, last)];
        sB2 = ssrc_p[min(e0 + 6, last)];
        sB3 = ssrc_p[min(e0 + 7, last)];
        for (int eb = e0; eb < e1; eb += 4) {
            int p0 = ssrc_p[min(eb + 8, last)];
            int p1 = ssrc_p[min(eb + 9, last)];
            int p2 = ssrc_p[min(eb + 10, last)];
            int p3 = ssrc_p[min(eb + 11, last)];
            uint4 v0 = *(const uint4*)(gs + (size_t)sB0 * 64);
            uint4 v1 = *(const uint4*)(gs + (size_t)sB1 * 64);
            uint4 v2 = *(const uint4*)(gs + (size_t)sB2 * 64);
            uint4 v3 = *(const uint4*)(gs + (size_t)sB3 * 64);
            uint4 z = make_uint4(0u, 0u, 0u, 0u);
            if (eb + 1 >= e1) uA1 = z;
            if (eb + 2 >= e1) uA2 = z;
            if (eb + 3 >= e1) uA3 = z;
            ACC8(uA0); ACC8(uA1); ACC8(uA2); ACC8(uA3);
            uA0 = v0; uA1 = v1; uA2 = v2; uA3 = v3;
            sB0 = p0; sB1 = p1; sB2 = p2; sB3 = p3;
        }
    }
    uint4 ud = *(const uint4*)(gs + (size_t)d * 64);
    ACC8(ud);
    float dv = dinv_p[di];
    const float* bp = b2 + fl * 8;
    float4 bb0 = *(const float4*)bp;
    float4 bb1 = *(const float4*)(bp + 4);
    float4 r0, r1;
    r0.x = a0 * dv + bb0.x;
    r0.y = a1 * dv + bb0.y;
    r0.z = a2 * dv + bb0.z;
    r0.w = a3 * dv + bb0.w;
    r1.x = a4 * dv + bb1.x;
    r1.y = a5 * dv + bb1.y;
    r1.z = a6 * dv + bb1.z;
    r1.w = a7 * dv + bb1.w;
    float* op = out + (size_t)d * OUTDIM + fl * 8;
    *(float4*)op = r0;
    *(float4*)(op + 4) = r1;
}

// ---------------- launch ----------------

extern "C" void kernel_launch(void* const* d_in, const int* in_sizes, int n_in,
                              void* d_out, int out_size, void* d_ws, size_t ws_size,
                              hipStream_t stream) {
    const float* x   = (const float*)d_in[0];
    const int*   ei  = (const int*)d_in[1];
    const float* W1  = (const float*)d_in[2];
    const float* b1  = (const float*)d_in[3];
    const float* W2  = (const float*)d_in[4];
    const float* b2  = (const float*)d_in[5];
    float* out = (float*)d_out;

    const int* row = ei;        // sources
    const int* col = ei + NE;   // destinations

    size_t off = 0;
    auto alloc = [&](size_t bytes) {
        void* p = (char*)d_ws + off;
        off += (bytes + 255) & ~(size_t)255;
        return p;
    };
    float*  dinv     = (float*) alloc((size_t)NN * 4);
    int*    rcur     = (int*)   alloc(NRANGE * 4);
    int*    bcnt     = (int*)   alloc((size_t)NRANGE * NBBLK * 4);   // 800 KB
    int*    bbase    = (int*)   alloc((size_t)NRANGE * NBBLK * 4);   // 800 KB
    uint*   staged   = (uint*)  alloc((size_t)NRANGE * ACAP * 4);    // 8 MB
    ushort* ssrc_p   = (ushort*)alloc((size_t)NE * 2);
    ushort* W1T      = (ushort*)alloc((size_t)INDIM * HIDIM * 2);
    ushort* W2T      = (ushort*)alloc((size_t)HIDIM * OUTDIM * 2);
    ushort* g1s      = (ushort*)alloc((size_t)NN * HIDIM * 2);
    ushort* hrb      = (ushort*)alloc((size_t)NN * HIDIM * 2);
    ushort* g2s      = (ushort*)alloc((size_t)NN * OUTDIM * 2);
    int*    perm     = (int*)   alloc((size_t)NN * 4);
    int*    row_ptr_p= (int*)   alloc((size_t)(NN + 1) * 4);
    float*  dinv_p   = (float*) alloc((size_t)NN * 4);

    const int nb32 = (NN + 31) / 32;         // 1563
    const int nb64 = (NN + 63) / 64;         // 782

    k_wt<<<(INDIM * HIDIM + HIDIM * OUTDIM + 255) / 256, 256, 0, stream>>>(W1, W2, W1T, W2T);

    k_bcnt<<<NBBLK, 256, 0, stream>>>(col, bcnt);
    k_bscan<<<NRANGE, 1024, 0, stream>>>(bcnt, bbase, rcur);
    k_bscat<<<NBBLK, 256, 0, stream>>>(row, col, bbase, staged);

    k_sort<<<NRANGE, 1024, 0, stream>>>(staged, rcur, dinv, dinv_p, row_ptr_p, perm, ssrc_p);

    k_gemm1<<<nb64, 256, 0, stream>>>(x, W1T, dinv, g1s, NN);
    k_agg1<<<nb32 * 2, 256, 0, stream>>>(g1s, dinv_p, row_ptr_p, ssrc_p, perm, b1, hrb);
    k_gemm2<<<nb64, 256, 0, stream>>>(hrb, W2T, dinv_p, perm, g2s, NN);
    k_agg2<<<nb32, 256, 0, stream>>>(g2s, dinv_p, row_ptr_p, ssrc_p, perm, b2, out);
}